// Round 4
// baseline (545.951 us; speedup 1.0000x reference)
//
#include <hip/hip_runtime.h>
#include <hip/hip_bf16.h>
#include <math.h>

// UniMP 2-layer TransformerConv. N=50000, E=800000, G=512, D=64 (edge 16).
// R4: separable edge-MLP: score = q.k + ea.(We.q); value corr = We^T.(sum w*ea).
// Precompute A = Wq.We^T/8 (64x16) once/call; qe=[N,16] fused into qkvs.
// agg: 4 waves/block, scalar node id via readfirstlane, CSR-ordered bf16 ea
// (one coalesced 128B load / 4 edges), aj accumulation replaces 16 FMA/edge.

typedef unsigned int uint32;
typedef unsigned short u16;

__device__ __forceinline__ uint32 f2bf(float x) {
    uint32 u = __float_as_uint(x);
    u += 0x7fffu + ((u >> 16) & 1u);
    return u >> 16;
}
__device__ __forceinline__ float bf2f(u16 h) {
    return __uint_as_float(((uint32)h) << 16);
}

// ---------------- CSR build ----------------

__global__ void hist_kernel(const int* __restrict__ dst, int* __restrict__ deg, int E) {
    int e = blockIdx.x * blockDim.x + threadIdx.x;
    if (e < E) atomicAdd(&deg[dst[e]], 1);
}

__global__ void scan1_kernel(const int* __restrict__ deg, int* __restrict__ row_ptr,
                             int* __restrict__ totals, int N) {
    __shared__ int sh[1024];
    int tid = threadIdx.x;
    int i = blockIdx.x * 1024 + tid;
    int d = (i < N) ? deg[i] : 0;
    int val = d;
    sh[tid] = val;
    __syncthreads();
    for (int off = 1; off < 1024; off <<= 1) {
        int add = (tid >= off) ? sh[tid - off] : 0;
        __syncthreads();
        val += add;
        sh[tid] = val;
        __syncthreads();
    }
    if (i < N) row_ptr[i] = val - d;
    if (tid == 1023) totals[blockIdx.x] = val;
}

// wave-parallel exclusive scan of block totals (nb <= 64)
__global__ void scan2_kernel(int* totals, int nb) {
    int lane = threadIdx.x;
    int v = (lane < nb) ? totals[lane] : 0;
    #pragma unroll
    for (int off = 1; off < 64; off <<= 1) {
        int t = __shfl_up(v, off);
        if (lane >= off) v += t;
    }
    int ex = __shfl_up(v, 1);
    if (lane == 0) ex = 0;
    if (lane < nb) totals[lane] = ex;
}

__global__ void scan3_kernel(int* __restrict__ row_ptr, const int* __restrict__ totals,
                             int N, int E) {
    int i = blockIdx.x * blockDim.x + threadIdx.x;
    if (i < N) row_ptr[i] += totals[i >> 10];
    if (i == 0) row_ptr[N] = E;
}

// scatter: csr_src + edge_attr -> bf16 in CSR order (kills eid indirection in agg)
__global__ void scatter_kernel(const int* __restrict__ src, const int* __restrict__ dst,
                               const int* __restrict__ row_ptr, int* __restrict__ fill,
                               const float* __restrict__ ea,
                               int* __restrict__ csr_src, u16* __restrict__ ea16, int E) {
    int e = blockIdx.x * blockDim.x + threadIdx.x;
    if (e >= E) return;
    int d = dst[e];
    int pos = row_ptr[d] + atomicAdd(&fill[d], 1);
    csr_src[pos] = src[e];
    const float4* ev = (const float4*)(ea + (size_t)e * 16);
    float4 q0 = ev[0], q1 = ev[1], q2 = ev[2], q3 = ev[3];
    uint32* o = (uint32*)(ea16 + (size_t)pos * 16);
    o[0] = f2bf(q0.x) | (f2bf(q0.y) << 16);
    o[1] = f2bf(q0.z) | (f2bf(q0.w) << 16);
    o[2] = f2bf(q1.x) | (f2bf(q1.y) << 16);
    o[3] = f2bf(q1.z) | (f2bf(q1.w) << 16);
    o[4] = f2bf(q2.x) | (f2bf(q2.y) << 16);
    o[5] = f2bf(q2.z) | (f2bf(q2.w) << 16);
    o[6] = f2bf(q3.x) | (f2bf(q3.y) << 16);
    o[7] = f2bf(q3.z) | (f2bf(q3.w) << 16);
}

// ---------------- weight precompute: A[d][j] = (Wq.We^T)[d][j]/8, be[j] = (bq.We^T)[j]/8 ----

__global__ void wqe_kernel(const float* __restrict__ wq1, const float* __restrict__ bq1,
                           const float* __restrict__ we1,
                           const float* __restrict__ wq2, const float* __restrict__ bq2,
                           const float* __restrict__ we2,
                           float* __restrict__ A1, float* __restrict__ be1,
                           float* __restrict__ A2, float* __restrict__ be2) {
    const float* wq = blockIdx.x ? wq2 : wq1;
    const float* bq = blockIdx.x ? bq2 : bq1;
    const float* we = blockIdx.x ? we2 : we1;
    float* A  = blockIdx.x ? A2 : A1;
    float* be = blockIdx.x ? be2 : be1;
    int t = threadIdx.x;
    for (int idx = t; idx < 64 * 16; idx += 256) {
        int dd = idx >> 4, j = idx & 15;
        float acc = 0.f;
        for (int c = 0; c < 64; ++c) acc = fmaf(wq[dd * 64 + c], we[j * 64 + c], acc);
        A[idx] = acc * 0.125f;
    }
    if (t < 16) {
        float acc = 0.f;
        for (int c = 0; c < 64; ++c) acc = fmaf(bq[c], we[t * 64 + c], acc);
        be[t] = acc * 0.125f;
    }
}

// ---------------- fused node linears ----------------
// blockIdx.y: 0 -> q (pre-scaled 1/8) + qe[N,16], 1 -> k&v packed bf16, 2 -> skip

__global__ __launch_bounds__(256) void qkvs_kernel(
    const float* __restrict__ xin,
    const float* __restrict__ wqm, const float* __restrict__ bqm,
    const float* __restrict__ wkm, const float* __restrict__ bkm,
    const float* __restrict__ wvm, const float* __restrict__ bvm,
    const float* __restrict__ wsm, const float* __restrict__ bsm,
    const float* __restrict__ Aq, const float* __restrict__ beq,
    float* __restrict__ qo, uint32* __restrict__ kvo,
    float* __restrict__ so, float* __restrict__ qeo, int N)
{
    int mtx = blockIdx.y;
    __shared__ float W0[64][64];
    __shared__ float W1[64][64];
    __shared__ float X[64][64];
    __shared__ float As[64][17];
    int t = threadIdx.x;
    int col = t & 63;
    int sub = t >> 6;

    const float* w0 = (mtx == 0) ? wqm : (mtx == 1) ? wkm : wsm;
    const float* b0p = (mtx == 0) ? bqm : (mtx == 1) ? bkm : bsm;
    for (int r = t; r < 4096; r += 256) W0[r >> 6][r & 63] = w0[r];
    if (mtx == 1)
        for (int r = t; r < 4096; r += 256) W1[r >> 6][r & 63] = wvm[r];
    if (mtx == 0)
        for (int r = t; r < 1024; r += 256) As[r >> 4][r & 15] = Aq[r];
    int n0 = blockIdx.x * 64;
    for (int r = t; r < 4096; r += 256) {
        int n = n0 + (r >> 6);
        X[r >> 6][r & 63] = (n < N) ? xin[(size_t)n * 64 + (r & 63)] : 0.f;
    }
    __syncthreads();

    float b0 = b0p[col];
    float b1 = (mtx == 1) ? bvm[col] : 0.f;

    for (int nb = sub * 16; nb < sub * 16 + 16; nb += 8) {
        float a0[8], a1[8];
        #pragma unroll
        for (int u = 0; u < 8; ++u) { a0[u] = b0; a1[u] = b1; }
        if (mtx == 1) {
            for (int j = 0; j < 64; ++j) {
                float wk_ = W0[j][col], wv_ = W1[j][col];
                #pragma unroll
                for (int u = 0; u < 8; ++u) {
                    float xv = X[nb + u][j];
                    a0[u] = fmaf(xv, wk_, a0[u]);
                    a1[u] = fmaf(xv, wv_, a1[u]);
                }
            }
        } else {
            for (int j = 0; j < 64; ++j) {
                float wj = W0[j][col];
                #pragma unroll
                for (int u = 0; u < 8; ++u) a0[u] = fmaf(X[nb + u][j], wj, a0[u]);
            }
        }
        #pragma unroll
        for (int u = 0; u < 8; ++u) {
            int n = n0 + nb + u;
            if (n < N) {
                if (mtx == 0)      qo[(size_t)n * 64 + col] = a0[u] * 0.125f;
                else if (mtx == 2) so[(size_t)n * 64 + col] = a0[u];
                else kvo[(size_t)n * 64 + col] = f2bf(a0[u]) | (f2bf(a1[u]) << 16);
            }
        }
    }

    if (mtx == 0) {
        // qe pass: X still valid (read-only since sync). 1024 outputs, 4 reps.
        #pragma unroll
        for (int rep = 0; rep < 4; ++rep) {
            int idx = rep * 256 + t;
            int n = idx >> 4, j = idx & 15;
            float acc = beq[j];
            for (int c = 0; c < 64; ++c) acc = fmaf(X[n][c], As[c][j], acc);
            int gn = n0 + n;
            if (gn < N) qeo[(size_t)gn * 16 + j] = acc;
        }
    }
}

// ---------------- per-node softmax aggregation ----------------
// 4 waves/block, one wave per node; lane = feature dim. Scalar node id via
// readfirstlane -> s_load for row_ptr/csr_src. score = q.k + ea.qe (one reduce).

__global__ __launch_bounds__(256) void agg_kernel(
    const float* __restrict__ q, const uint32* __restrict__ kv,
    const float* __restrict__ qe, const float* __restrict__ we,
    const u16* __restrict__ ea16,
    const int* __restrict__ row_ptr, const int* __restrict__ csr_src,
    const float* __restrict__ skip_in, float* __restrict__ hout,
    const int* __restrict__ batch, float* __restrict__ pooled, int N)
{
    int lane = threadIdx.x & 63;
    int wid = (blockIdx.x << 2) + (threadIdx.x >> 6);
    if (wid >= N) return;
    int i = __builtin_amdgcn_readfirstlane(wid);

    int grp = lane >> 4;
    float wer[16];
    #pragma unroll
    for (int j = 0; j < 16; ++j) wer[j] = we[j * 64 + lane];
    float ql = q[(size_t)i * 64 + lane];                    // pre-scaled 1/8
    float qel = qe[(size_t)i * 16 + (lane & 15)];           // pre-scaled 1/8

    float den = 0.f, o = 0.f, aj = 0.f;
    int beg = row_ptr[i], end = row_ptr[i + 1];

    int p = beg;
    for (; p + 4 <= end; p += 4) {
        int s0 = csr_src[p],     s1 = csr_src[p + 1];
        int s2 = csr_src[p + 2], s3 = csr_src[p + 3];
        uint32 kb0 = kv[(size_t)s0 * 64 + lane];
        uint32 kb1 = kv[(size_t)s1 * 64 + lane];
        uint32 kb2 = kv[(size_t)s2 * 64 + lane];
        uint32 kb3 = kv[(size_t)s3 * 64 + lane];
        float eav = bf2f(ea16[(size_t)p * 16 + lane]);      // 4 edges' attrs across wave
        float ep = eav * qel;
        ep += __shfl_xor(ep, 1); ep += __shfl_xor(ep, 2);
        ep += __shfl_xor(ep, 4); ep += __shfl_xor(ep, 8);   // per-16 group sums
        uint32 kbs[4] = {kb0, kb1, kb2, kb3};
        float w4[4];
        #pragma unroll
        for (int u = 0; u < 4; ++u) {
            float kl = __uint_as_float(kbs[u] << 16);
            float part = ql * kl;
            part += __shfl_xor(part, 1);  part += __shfl_xor(part, 2);
            part += __shfl_xor(part, 4);  part += __shfl_xor(part, 8);
            part += __shfl_xor(part, 16); part += __shfl_xor(part, 32);
            float sc = part + __shfl(ep, u * 16);
            w4[u] = __expf(sc);
        }
        den += (w4[0] + w4[1]) + (w4[2] + w4[3]);
        #pragma unroll
        for (int u = 0; u < 4; ++u) {
            float vl = __uint_as_float(kbs[u] & 0xffff0000u);
            o = fmaf(w4[u], vl, o);
        }
        float wv = (grp == 0) ? w4[0] : (grp == 1) ? w4[1] : (grp == 2) ? w4[2] : w4[3];
        aj = fmaf(wv, eav, aj);
    }
    for (; p < end; ++p) {
        int s = csr_src[p];
        uint32 kb = kv[(size_t)s * 64 + lane];
        float eav = 0.f;
        if (lane < 16) eav = bf2f(ea16[(size_t)p * 16 + lane]);
        float kl = __uint_as_float(kb << 16);
        float part = fmaf(ql, kl, eav * qel);
        #pragma unroll
        for (int off = 32; off; off >>= 1) part += __shfl_xor(part, off);
        float w = __expf(part);
        den += w;
        o = fmaf(w, __uint_as_float(kb & 0xffff0000u), o);
        aj = fmaf(w, eav, aj);
    }

    // fold aj groups, apply value correction o += sum_j aj[j]*We[j][lane]
    aj += __shfl_xor(aj, 16);
    aj += __shfl_xor(aj, 32);
    #pragma unroll
    for (int j = 0; j < 16; ++j) o = fmaf(__shfl(aj, j), wer[j], o);

    float dinv = (den > 0.f) ? 1.f / den : 0.f;
    float r = fmaf(o, dinv, skip_in[(size_t)i * 64 + lane]);
    r = (r >= 0.f) ? r : 0.01f * r;
    hout[(size_t)i * 64 + lane] = r;
    if (pooled) atomicAdd(&pooled[(size_t)batch[i] * 64 + lane], r);
}

// ---------------- head ----------------

__global__ void head_kernel(const float* __restrict__ pooled,
                            const float* __restrict__ w1, const float* __restrict__ b1,
                            const float* __restrict__ w2, const float* __restrict__ b2,
                            float* __restrict__ out, int G) {
    int g = blockIdx.x;
    int lane = threadIdx.x;
    __shared__ float hl[64];
    float p = pooled[g * 64 + lane];
    float ss = p * p;
    #pragma unroll
    for (int off = 32; off; off >>= 1) ss += __shfl_xor(ss, off);
    float hn = p / fmaxf(sqrtf(ss), 1e-12f);
    hl[lane] = hn;
    __syncthreads();
    float acc = b1[lane];
    #pragma unroll
    for (int j = 0; j < 64; ++j) acc = fmaf(hl[j], w1[j * 64 + lane], acc);
    acc = (acc >= 0.f) ? acc : 0.01f * acc;
    float r = acc * w2[lane];
    #pragma unroll
    for (int off = 32; off; off >>= 1) r += __shfl_xor(r, off);
    if (lane == 0) out[g] = r + b2[0];
}

// ---------------- launch ----------------

extern "C" void kernel_launch(void* const* d_in, const int* in_sizes, int n_in,
                              void* d_out, int out_size, void* d_ws, size_t ws_size,
                              hipStream_t stream) {
    const float* x     = (const float*)d_in[0];
    const int*   ei    = (const int*)  d_in[1];
    const float* ea    = (const float*)d_in[2];
    const int*   batch = (const int*)  d_in[3];
    const float *wq1=(const float*)d_in[4],  *bq1=(const float*)d_in[5];
    const float *wk1=(const float*)d_in[6],  *bk1=(const float*)d_in[7];
    const float *wv1=(const float*)d_in[8],  *bv1=(const float*)d_in[9];
    const float *we1=(const float*)d_in[10];
    const float *ws1=(const float*)d_in[11], *bs1=(const float*)d_in[12];
    const float *wq2=(const float*)d_in[13], *bq2=(const float*)d_in[14];
    const float *wk2=(const float*)d_in[15], *bk2=(const float*)d_in[16];
    const float *wv2=(const float*)d_in[17], *bv2=(const float*)d_in[18];
    const float *we2=(const float*)d_in[19];
    const float *ws2=(const float*)d_in[20], *bs2=(const float*)d_in[21];
    const float *wf1=(const float*)d_in[22], *bf1=(const float*)d_in[23];
    const float *wf2=(const float*)d_in[24], *bf2=(const float*)d_in[25];

    int N = in_sizes[0] / 64;
    int E = in_sizes[2] / 16;
    int G = out_size - N * 64;

    const int* srcA = ei;
    const int* dstA = ei + E;

    char* w = (char*)d_ws;
    float*  qb      = (float*)w;  w += (size_t)N * 64 * 4;
    uint32* kvb     = (uint32*)w; w += (size_t)N * 64 * 4;
    float*  hb      = (float*)w;  w += (size_t)N * 64 * 4;
    float*  qeb     = (float*)w;  w += (size_t)N * 16 * 4;
    float*  pooled  = (float*)w;  w += (size_t)G * 64 * 4;
    int* row_ptr    = (int*)w;    w += (size_t)(N + 1) * 4;
    int* totals     = (int*)w;    w += 256 * 4;
    float* A1       = (float*)w;  w += 1024 * 4;
    float* be1      = (float*)w;  w += 16 * 4;
    float* A2       = (float*)w;  w += 1024 * 4;
    float* be2      = (float*)w;  w += 16 * 4;
    int* csr_src    = (int*)w;    w += (size_t)E * 4;
    u16* ea16       = (u16*)w;    w += (size_t)(E * 16 + 64) * 2;
    // deg/fill overlaid into qb: dead once scatter completes, before qkvs writes qb
    int* deg  = (int*)qb;
    int* fill = (int*)qb + N;

    hipMemsetAsync(deg, 0, (size_t)2 * N * 4, stream);
    hipMemsetAsync(pooled, 0, (size_t)G * 64 * 4, stream);

    const int TB = 256;
    wqe_kernel<<<2, 256, 0, stream>>>(wq1, bq1, we1, wq2, bq2, we2, A1, be1, A2, be2);
    hist_kernel<<<(E + TB - 1) / TB, TB, 0, stream>>>(dstA, deg, E);
    int nb = (N + 1023) / 1024;
    scan1_kernel<<<nb, 1024, 0, stream>>>(deg, row_ptr, totals, N);
    scan2_kernel<<<1, 64, 0, stream>>>(totals, nb);
    scan3_kernel<<<(N + TB - 1) / TB, TB, 0, stream>>>(row_ptr, totals, N, E);
    scatter_kernel<<<(E + TB - 1) / TB, TB, 0, stream>>>(srcA, dstA, row_ptr, fill, ea,
                                                         csr_src, ea16, E);

    float* outp = (float*)d_out;
    float* atom = outp + G;

    dim3 qgrid((N + 63) / 64, 3);
    int aggBlocks = (N + 3) / 4;

    qkvs_kernel<<<qgrid, 256, 0, stream>>>(x, wq1, bq1, wk1, bk1, wv1, bv1, ws1, bs1,
                                           A1, be1, qb, kvb, hb, qeb, N);
    agg_kernel<<<aggBlocks, 256, 0, stream>>>(qb, kvb, qeb, we1, ea16, row_ptr, csr_src,
                                              hb, hb, nullptr, nullptr, N);

    qkvs_kernel<<<qgrid, 256, 0, stream>>>(hb, wq2, bq2, wk2, bk2, wv2, bv2, ws2, bs2,
                                           A2, be2, qb, kvb, atom, qeb, N);
    agg_kernel<<<aggBlocks, 256, 0, stream>>>(qb, kvb, qeb, we2, ea16, row_ptr, csr_src,
                                              atom, atom, batch, pooled, N);

    head_kernel<<<G, 64, 0, stream>>>(pooled, wf1, bf1, wf2, bf2, outp, G);
}

// Round 5
// 455.435 us; speedup vs baseline: 1.1987x; 1.1987x over previous
//
#include <hip/hip_runtime.h>
#include <hip/hip_bf16.h>
#include <math.h>

// UniMP 2-layer TransformerConv. N=50000, E=800000, G=512, D=64 (edge 16).
// R5: feature-blocked agg layout: lane holds 4 consecutive features (16 lanes/edge,
// 4 edges per wave iteration). Score reduce = 4-level xor within 16 lanes (1 DS/edge
// vs 8 in R4); kv gather = one dwordx4 per lane per 4 edges; one expf per 4 edges.
// Epilogue per node folds groups + transposes + applies We value-correction.

typedef unsigned int uint32;
typedef unsigned short u16;

__device__ __forceinline__ uint32 f2bf(float x) {
    uint32 u = __float_as_uint(x);
    u += 0x7fffu + ((u >> 16) & 1u);
    return u >> 16;
}
__device__ __forceinline__ float bf2f(u16 h) {
    return __uint_as_float(((uint32)h) << 16);
}

// ---------------- CSR build ----------------

__global__ void hist_kernel(const int* __restrict__ dst, int* __restrict__ deg, int E) {
    int e = blockIdx.x * blockDim.x + threadIdx.x;
    if (e < E) atomicAdd(&deg[dst[e]], 1);
}

__global__ void scan1_kernel(const int* __restrict__ deg, int* __restrict__ row_ptr,
                             int* __restrict__ totals, int N) {
    __shared__ int sh[1024];
    int tid = threadIdx.x;
    int i = blockIdx.x * 1024 + tid;
    int d = (i < N) ? deg[i] : 0;
    int val = d;
    sh[tid] = val;
    __syncthreads();
    for (int off = 1; off < 1024; off <<= 1) {
        int add = (tid >= off) ? sh[tid - off] : 0;
        __syncthreads();
        val += add;
        sh[tid] = val;
        __syncthreads();
    }
    if (i < N) row_ptr[i] = val - d;
    if (tid == 1023) totals[blockIdx.x] = val;
}

__global__ void scan2_kernel(int* totals, int nb) {
    int lane = threadIdx.x;
    int v = (lane < nb) ? totals[lane] : 0;
    #pragma unroll
    for (int off = 1; off < 64; off <<= 1) {
        int t = __shfl_up(v, off);
        if (lane >= off) v += t;
    }
    int ex = __shfl_up(v, 1);
    if (lane == 0) ex = 0;
    if (lane < nb) totals[lane] = ex;
}

__global__ void scan3_kernel(int* __restrict__ row_ptr, const int* __restrict__ totals,
                             int N, int E) {
    int i = blockIdx.x * blockDim.x + threadIdx.x;
    if (i < N) row_ptr[i] += totals[i >> 10];
    if (i == 0) row_ptr[N] = E;
}

// scatter: csr_src + edge_attr -> bf16 in CSR order
__global__ void scatter_kernel(const int* __restrict__ src, const int* __restrict__ dst,
                               const int* __restrict__ row_ptr, int* __restrict__ fill,
                               const float* __restrict__ ea,
                               int* __restrict__ csr_src, u16* __restrict__ ea16, int E) {
    int e = blockIdx.x * blockDim.x + threadIdx.x;
    if (e >= E) return;
    int d = dst[e];
    int pos = row_ptr[d] + atomicAdd(&fill[d], 1);
    csr_src[pos] = src[e];
    const float4* ev = (const float4*)(ea + (size_t)e * 16);
    float4 q0 = ev[0], q1 = ev[1], q2 = ev[2], q3 = ev[3];
    uint32* o = (uint32*)(ea16 + (size_t)pos * 16);
    o[0] = f2bf(q0.x) | (f2bf(q0.y) << 16);
    o[1] = f2bf(q0.z) | (f2bf(q0.w) << 16);
    o[2] = f2bf(q1.x) | (f2bf(q1.y) << 16);
    o[3] = f2bf(q1.z) | (f2bf(q1.w) << 16);
    o[4] = f2bf(q2.x) | (f2bf(q2.y) << 16);
    o[5] = f2bf(q2.z) | (f2bf(q2.w) << 16);
    o[6] = f2bf(q3.x) | (f2bf(q3.y) << 16);
    o[7] = f2bf(q3.z) | (f2bf(q3.w) << 16);
}

// ---------------- weight precompute: A = (Wq.We^T)/8, be = (bq.We^T)/8 ----------------

__global__ void wqe_kernel(const float* __restrict__ wq1, const float* __restrict__ bq1,
                           const float* __restrict__ we1,
                           const float* __restrict__ wq2, const float* __restrict__ bq2,
                           const float* __restrict__ we2,
                           float* __restrict__ A1, float* __restrict__ be1,
                           float* __restrict__ A2, float* __restrict__ be2) {
    const float* wq = blockIdx.x ? wq2 : wq1;
    const float* bq = blockIdx.x ? bq2 : bq1;
    const float* we = blockIdx.x ? we2 : we1;
    float* A  = blockIdx.x ? A2 : A1;
    float* be = blockIdx.x ? be2 : be1;
    int t = threadIdx.x;
    for (int idx = t; idx < 64 * 16; idx += 256) {
        int dd = idx >> 4, j = idx & 15;
        float acc = 0.f;
        for (int c = 0; c < 64; ++c) acc = fmaf(wq[dd * 64 + c], we[j * 64 + c], acc);
        A[idx] = acc * 0.125f;
    }
    if (t < 16) {
        float acc = 0.f;
        for (int c = 0; c < 64; ++c) acc = fmaf(bq[c], we[t * 64 + c], acc);
        be[t] = acc * 0.125f;
    }
}

// ---------------- fused node linears ----------------
// blockIdx.y: 0 -> q (pre-scaled 1/8) + qe[N,16], 1 -> k&v packed bf16, 2 -> skip

__global__ __launch_bounds__(256) void qkvs_kernel(
    const float* __restrict__ xin,
    const float* __restrict__ wqm, const float* __restrict__ bqm,
    const float* __restrict__ wkm, const float* __restrict__ bkm,
    const float* __restrict__ wvm, const float* __restrict__ bvm,
    const float* __restrict__ wsm, const float* __restrict__ bsm,
    const float* __restrict__ Aq, const float* __restrict__ beq,
    float* __restrict__ qo, uint32* __restrict__ kvo,
    float* __restrict__ so, float* __restrict__ qeo, int N)
{
    int mtx = blockIdx.y;
    __shared__ float W0[64][64];
    __shared__ float W1[64][64];
    __shared__ float X[64][64];
    __shared__ float As[64][17];
    int t = threadIdx.x;
    int col = t & 63;
    int sub = t >> 6;

    const float* w0 = (mtx == 0) ? wqm : (mtx == 1) ? wkm : wsm;
    const float* b0p = (mtx == 0) ? bqm : (mtx == 1) ? bkm : bsm;
    for (int r = t; r < 1024; r += 256) ((float4*)W0)[r] = ((const float4*)w0)[r];
    if (mtx == 1)
        for (int r = t; r < 1024; r += 256) ((float4*)W1)[r] = ((const float4*)wvm)[r];
    if (mtx == 0)
        for (int r = t; r < 1024; r += 256) As[r >> 4][r & 15] = Aq[r];
    int n0 = blockIdx.x * 64;
    if (n0 + 64 <= N) {
        const float4* xi4 = (const float4*)(xin + (size_t)n0 * 64);
        for (int r = t; r < 1024; r += 256) ((float4*)X)[r] = xi4[r];
    } else {
        for (int r = t; r < 4096; r += 256) {
            int n = n0 + (r >> 6);
            X[r >> 6][r & 63] = (n < N) ? xin[(size_t)n * 64 + (r & 63)] : 0.f;
        }
    }
    __syncthreads();

    float b0 = b0p[col];
    float b1 = (mtx == 1) ? bvm[col] : 0.f;

    for (int nb = sub * 16; nb < sub * 16 + 16; nb += 8) {
        float a0[8], a1[8];
        #pragma unroll
        for (int u = 0; u < 8; ++u) { a0[u] = b0; a1[u] = b1; }
        if (mtx == 1) {
            for (int j = 0; j < 64; ++j) {
                float wk_ = W0[j][col], wv_ = W1[j][col];
                #pragma unroll
                for (int u = 0; u < 8; ++u) {
                    float xv = X[nb + u][j];
                    a0[u] = fmaf(xv, wk_, a0[u]);
                    a1[u] = fmaf(xv, wv_, a1[u]);
                }
            }
        } else {
            for (int j = 0; j < 64; ++j) {
                float wj = W0[j][col];
                #pragma unroll
                for (int u = 0; u < 8; ++u) a0[u] = fmaf(X[nb + u][j], wj, a0[u]);
            }
        }
        #pragma unroll
        for (int u = 0; u < 8; ++u) {
            int n = n0 + nb + u;
            if (n < N) {
                if (mtx == 0)      qo[(size_t)n * 64 + col] = a0[u] * 0.125f;
                else if (mtx == 2) so[(size_t)n * 64 + col] = a0[u];
                else kvo[(size_t)n * 64 + col] = f2bf(a0[u]) | (f2bf(a1[u]) << 16);
            }
        }
    }

    if (mtx == 0) {
        #pragma unroll
        for (int rep = 0; rep < 4; ++rep) {
            int idx = rep * 256 + t;
            int n = idx >> 4, j = idx & 15;
            float acc = beq[j];
            for (int c = 0; c < 64; ++c) acc = fmaf(X[n][c], As[c][j], acc);
            int gn = n0 + n;
            if (gn < N) qeo[(size_t)gn * 16 + j] = acc;
        }
    }
}

// ---------------- per-node softmax aggregation (feature-blocked) ----------------
// 4 waves/block, one wave per node. Lane (g,p): g=lane>>4 (edge slot), p=lane&15
// (feature block). Lane holds features 4p..4p+3. Per iteration: 4 edges, one
// dwordx4 kv gather/lane, fused score reduce in 4 xor levels, one expf.

__global__ __launch_bounds__(256) void agg_kernel(
    const float* __restrict__ q, const uint32* __restrict__ kv,
    const float* __restrict__ qe, const float* __restrict__ we,
    const u16* __restrict__ ea16,
    const int* __restrict__ row_ptr, const int* __restrict__ csr_src,
    const float* __restrict__ skip_in, float* __restrict__ hout,
    const int* __restrict__ batch, float* __restrict__ pooled, int N)
{
    int lane = threadIdx.x & 63;
    int wid = (blockIdx.x << 2) + (threadIdx.x >> 6);
    if (wid >= N) return;
    int i = __builtin_amdgcn_readfirstlane(wid);

    int grp = lane >> 4;
    int pos = lane & 15;

    // q features 4p..4p+3 (pre-scaled 1/8), qe[p] (pre-scaled 1/8)
    float4 qv = ((const float4*)(q + (size_t)i * 64))[pos];
    float qel = qe[(size_t)i * 16 + pos];
    // We in per-feature layout for epilogue correction
    float wer[16];
    #pragma unroll
    for (int j = 0; j < 16; ++j) wer[j] = we[j * 64 + lane];

    float den = 0.f, aj = 0.f;
    float o4x = 0.f, o4y = 0.f, o4z = 0.f, o4w = 0.f;

    int beg = row_ptr[i], end = row_ptr[i + 1];
    for (int p = beg; p < end; p += 4) {
        int eg = p + grp;
        int sidx = (eg < end) ? eg : (end - 1);
        int s = csr_src[sidx];
        uint4 kb = ((const uint4*)(kv + (size_t)s * 64))[pos];
        float eav = bf2f(ea16[(size_t)p * 16 + lane]);

        float part = eav * qel;
        part = fmaf(qv.x, __uint_as_float(kb.x << 16), part);
        part = fmaf(qv.y, __uint_as_float(kb.y << 16), part);
        part = fmaf(qv.z, __uint_as_float(kb.z << 16), part);
        part = fmaf(qv.w, __uint_as_float(kb.w << 16), part);
        part += __shfl_xor(part, 1);
        part += __shfl_xor(part, 2);
        part += __shfl_xor(part, 4);
        part += __shfl_xor(part, 8);
        float sc = (eg < end) ? part : -1e30f;
        float w = __expf(sc);

        den += w;
        aj = fmaf(w, eav, aj);
        o4x = fmaf(w, __uint_as_float(kb.x & 0xffff0000u), o4x);
        o4y = fmaf(w, __uint_as_float(kb.y & 0xffff0000u), o4y);
        o4z = fmaf(w, __uint_as_float(kb.z & 0xffff0000u), o4z);
        o4w = fmaf(w, __uint_as_float(kb.w & 0xffff0000u), o4w);
    }

    // fold across the 4 edge-slot groups
    o4x += __shfl_xor(o4x, 16); o4x += __shfl_xor(o4x, 32);
    o4y += __shfl_xor(o4y, 16); o4y += __shfl_xor(o4y, 32);
    o4z += __shfl_xor(o4z, 16); o4z += __shfl_xor(o4z, 32);
    o4w += __shfl_xor(o4w, 16); o4w += __shfl_xor(o4w, 32);
    aj  += __shfl_xor(aj, 16);  aj  += __shfl_xor(aj, 32);
    den += __shfl_xor(den, 16); den += __shfl_xor(den, 32);

    // transpose o to lane=feature: lane l wants feature l = block (l>>2), reg (l&3)
    int srcl = lane >> 2;
    float t0 = __shfl(o4x, srcl), t1 = __shfl(o4y, srcl);
    float t2 = __shfl(o4z, srcl), t3 = __shfl(o4w, srcl);
    int r2 = lane & 3;
    float o = (r2 == 0) ? t0 : (r2 == 1) ? t1 : (r2 == 2) ? t2 : t3;

    // value correction: o[f] += sum_j aj[j] * We[j][f]
    #pragma unroll
    for (int j = 0; j < 16; ++j) o = fmaf(__shfl(aj, j), wer[j], o);

    float dinv = (den > 0.f) ? 1.f / den : 0.f;
    float r = fmaf(o, dinv, skip_in[(size_t)i * 64 + lane]);
    r = (r >= 0.f) ? r : 0.01f * r;
    hout[(size_t)i * 64 + lane] = r;
    if (pooled) atomicAdd(&pooled[(size_t)batch[i] * 64 + lane], r);
}

// ---------------- head ----------------

__global__ void head_kernel(const float* __restrict__ pooled,
                            const float* __restrict__ w1, const float* __restrict__ b1,
                            const float* __restrict__ w2, const float* __restrict__ b2,
                            float* __restrict__ out, int G) {
    int g = blockIdx.x;
    int lane = threadIdx.x;
    __shared__ float hl[64];
    float p = pooled[g * 64 + lane];
    float ss = p * p;
    #pragma unroll
    for (int off = 32; off; off >>= 1) ss += __shfl_xor(ss, off);
    float hn = p / fmaxf(sqrtf(ss), 1e-12f);
    hl[lane] = hn;
    __syncthreads();
    float acc = b1[lane];
    #pragma unroll
    for (int j = 0; j < 64; ++j) acc = fmaf(hl[j], w1[j * 64 + lane], acc);
    acc = (acc >= 0.f) ? acc : 0.01f * acc;
    float r = acc * w2[lane];
    #pragma unroll
    for (int off = 32; off; off >>= 1) r += __shfl_xor(r, off);
    if (lane == 0) out[g] = r + b2[0];
}

// ---------------- launch ----------------

extern "C" void kernel_launch(void* const* d_in, const int* in_sizes, int n_in,
                              void* d_out, int out_size, void* d_ws, size_t ws_size,
                              hipStream_t stream) {
    const float* x     = (const float*)d_in[0];
    const int*   ei    = (const int*)  d_in[1];
    const float* ea    = (const float*)d_in[2];
    const int*   batch = (const int*)  d_in[3];
    const float *wq1=(const float*)d_in[4],  *bq1=(const float*)d_in[5];
    const float *wk1=(const float*)d_in[6],  *bk1=(const float*)d_in[7];
    const float *wv1=(const float*)d_in[8],  *bv1=(const float*)d_in[9];
    const float *we1=(const float*)d_in[10];
    const float *ws1=(const float*)d_in[11], *bs1=(const float*)d_in[12];
    const float *wq2=(const float*)d_in[13], *bq2=(const float*)d_in[14];
    const float *wk2=(const float*)d_in[15], *bk2=(const float*)d_in[16];
    const float *wv2=(const float*)d_in[17], *bv2=(const float*)d_in[18];
    const float *we2=(const float*)d_in[19];
    const float *ws2=(const float*)d_in[20], *bs2=(const float*)d_in[21];
    const float *wf1=(const float*)d_in[22], *bf1=(const float*)d_in[23];
    const float *wf2=(const float*)d_in[24], *bf2=(const float*)d_in[25];

    int N = in_sizes[0] / 64;
    int E = in_sizes[2] / 16;
    int G = out_size - N * 64;

    const int* srcA = ei;
    const int* dstA = ei + E;

    char* w = (char*)d_ws;
    float*  qb      = (float*)w;  w += (size_t)N * 64 * 4;
    uint32* kvb     = (uint32*)w; w += (size_t)N * 64 * 4;
    float*  hb      = (float*)w;  w += (size_t)N * 64 * 4;
    float*  qeb     = (float*)w;  w += (size_t)N * 16 * 4;
    float*  pooled  = (float*)w;  w += (size_t)G * 64 * 4;
    int* row_ptr    = (int*)w;    w += (size_t)(N + 1) * 4;
    int* totals     = (int*)w;    w += 256 * 4;
    float* A1       = (float*)w;  w += 1024 * 4;
    float* be1      = (float*)w;  w += 16 * 4;
    float* A2       = (float*)w;  w += 1024 * 4;
    float* be2      = (float*)w;  w += 16 * 4;
    int* csr_src    = (int*)w;    w += (size_t)E * 4;
    u16* ea16       = (u16*)w;    w += (size_t)(E * 16 + 64) * 2;
    int* deg  = (int*)qb;       // dead ranges of qb before qkvs writes it
    int* fill = (int*)qb + N;

    hipMemsetAsync(deg, 0, (size_t)2 * N * 4, stream);
    hipMemsetAsync(pooled, 0, (size_t)G * 64 * 4, stream);

    const int TB = 256;
    wqe_kernel<<<2, 256, 0, stream>>>(wq1, bq1, we1, wq2, bq2, we2, A1, be1, A2, be2);
    hist_kernel<<<(E + TB - 1) / TB, TB, 0, stream>>>(dstA, deg, E);
    int nb = (N + 1023) / 1024;
    scan1_kernel<<<nb, 1024, 0, stream>>>(deg, row_ptr, totals, N);
    scan2_kernel<<<1, 64, 0, stream>>>(totals, nb);
    scan3_kernel<<<(N + TB - 1) / TB, TB, 0, stream>>>(row_ptr, totals, N, E);
    scatter_kernel<<<(E + TB - 1) / TB, TB, 0, stream>>>(srcA, dstA, row_ptr, fill, ea,
                                                         csr_src, ea16, E);

    float* outp = (float*)d_out;
    float* atom = outp + G;

    dim3 qgrid((N + 63) / 64, 3);
    int aggBlocks = (N + 3) / 4;

    qkvs_kernel<<<qgrid, 256, 0, stream>>>(x, wq1, bq1, wk1, bk1, wv1, bv1, ws1, bs1,
                                           A1, be1, qb, kvb, hb, qeb, N);
    agg_kernel<<<aggBlocks, 256, 0, stream>>>(qb, kvb, qeb, we1, ea16, row_ptr, csr_src,
                                              hb, hb, nullptr, nullptr, N);

    qkvs_kernel<<<qgrid, 256, 0, stream>>>(hb, wq2, bq2, wk2, bk2, wv2, bv2, ws2, bs2,
                                           A2, be2, qb, kvb, atom, qeb, N);
    agg_kernel<<<aggBlocks, 256, 0, stream>>>(qb, kvb, qeb, we2, ea16, row_ptr, csr_src,
                                              atom, atom, batch, pooled, N);

    head_kernel<<<G, 64, 0, stream>>>(pooled, wf1, bf1, wf2, bf2, outp, G);
}

// Round 6
// 449.414 us; speedup vs baseline: 1.2148x; 1.0134x over previous
//
#include <hip/hip_runtime.h>
#include <hip/hip_bf16.h>
#include <math.h>

// UniMP 2-layer TransformerConv. N=50000, E=800000, G=512, D=64 (edge 16).
// R6: scatter split: light scatter writes csr_eid only (4B random); convert kernel
// does CSR-slot-parallel gather of src/ea (random READS, coalesced WRITES) -> kills
// the 102MB write-amplification. agg: 8 edges/iter, two independent reduce chains.

typedef unsigned int uint32;
typedef unsigned short u16;

__device__ __forceinline__ uint32 f2bf(float x) {
    uint32 u = __float_as_uint(x);
    u += 0x7fffu + ((u >> 16) & 1u);
    return u >> 16;
}
__device__ __forceinline__ float bf2f(u16 h) {
    return __uint_as_float(((uint32)h) << 16);
}

// ---------------- CSR build ----------------

__global__ void hist_kernel(const int* __restrict__ dst, int* __restrict__ deg, int E) {
    int e = blockIdx.x * blockDim.x + threadIdx.x;
    if (e < E) atomicAdd(&deg[dst[e]], 1);
}

__global__ void scan1_kernel(const int* __restrict__ deg, int* __restrict__ row_ptr,
                             int* __restrict__ totals, int N) {
    __shared__ int sh[1024];
    int tid = threadIdx.x;
    int i = blockIdx.x * 1024 + tid;
    int d = (i < N) ? deg[i] : 0;
    int val = d;
    sh[tid] = val;
    __syncthreads();
    for (int off = 1; off < 1024; off <<= 1) {
        int add = (tid >= off) ? sh[tid - off] : 0;
        __syncthreads();
        val += add;
        sh[tid] = val;
        __syncthreads();
    }
    if (i < N) row_ptr[i] = val - d;
    if (tid == 1023) totals[blockIdx.x] = val;
}

__global__ void scan2_kernel(int* totals, int nb) {
    int lane = threadIdx.x;
    int v = (lane < nb) ? totals[lane] : 0;
    #pragma unroll
    for (int off = 1; off < 64; off <<= 1) {
        int t = __shfl_up(v, off);
        if (lane >= off) v += t;
    }
    int ex = __shfl_up(v, 1);
    if (lane == 0) ex = 0;
    if (lane < nb) totals[lane] = ex;
}

__global__ void scan3_kernel(int* __restrict__ row_ptr, const int* __restrict__ totals,
                             int N, int E) {
    int i = blockIdx.x * blockDim.x + threadIdx.x;
    if (i < N) row_ptr[i] += totals[i >> 10];
    if (i == 0) row_ptr[N] = E;
}

// light scatter: only csr_eid (4B random write per edge)
__global__ void scatter_kernel(const int* __restrict__ dst, const int* __restrict__ row_ptr,
                               int* __restrict__ fill, int* __restrict__ csr_eid, int E) {
    int e = blockIdx.x * blockDim.x + threadIdx.x;
    if (e < E) {
        int d = dst[e];
        int pos = row_ptr[d] + atomicAdd(&fill[d], 1);
        csr_eid[pos] = e;
    }
}

// CSR-slot-parallel convert: coalesced eid read, random src/ea GATHERS,
// coalesced csr_src + ea16 writes.
__global__ void convert_kernel(const int* __restrict__ csr_eid, const int* __restrict__ src,
                               const float* __restrict__ ea,
                               int* __restrict__ csr_src, u16* __restrict__ ea16, int E) {
    int p = blockIdx.x * blockDim.x + threadIdx.x;
    if (p >= E) return;
    int e = csr_eid[p];
    csr_src[p] = src[e];
    const float4* ev = (const float4*)(ea + (size_t)e * 16);
    float4 q0 = ev[0], q1 = ev[1], q2 = ev[2], q3 = ev[3];
    uint32* o = (uint32*)(ea16 + (size_t)p * 16);
    o[0] = f2bf(q0.x) | (f2bf(q0.y) << 16);
    o[1] = f2bf(q0.z) | (f2bf(q0.w) << 16);
    o[2] = f2bf(q1.x) | (f2bf(q1.y) << 16);
    o[3] = f2bf(q1.z) | (f2bf(q1.w) << 16);
    o[4] = f2bf(q2.x) | (f2bf(q2.y) << 16);
    o[5] = f2bf(q2.z) | (f2bf(q2.w) << 16);
    o[6] = f2bf(q3.x) | (f2bf(q3.y) << 16);
    o[7] = f2bf(q3.z) | (f2bf(q3.w) << 16);
}

// ---------------- weight precompute: A = (Wq.We^T)/8, be = (bq.We^T)/8 ----------------

__global__ void wqe_kernel(const float* __restrict__ wq1, const float* __restrict__ bq1,
                           const float* __restrict__ we1,
                           const float* __restrict__ wq2, const float* __restrict__ bq2,
                           const float* __restrict__ we2,
                           float* __restrict__ A1, float* __restrict__ be1,
                           float* __restrict__ A2, float* __restrict__ be2) {
    const float* wq = blockIdx.x ? wq2 : wq1;
    const float* bq = blockIdx.x ? bq2 : bq1;
    const float* we = blockIdx.x ? we2 : we1;
    float* A  = blockIdx.x ? A2 : A1;
    float* be = blockIdx.x ? be2 : be1;
    int t = threadIdx.x;
    for (int idx = t; idx < 64 * 16; idx += 256) {
        int dd = idx >> 4, j = idx & 15;
        float acc = 0.f;
        for (int c = 0; c < 64; ++c) acc = fmaf(wq[dd * 64 + c], we[j * 64 + c], acc);
        A[idx] = acc * 0.125f;
    }
    if (t < 16) {
        float acc = 0.f;
        for (int c = 0; c < 64; ++c) acc = fmaf(bq[c], we[t * 64 + c], acc);
        be[t] = acc * 0.125f;
    }
}

// ---------------- fused node linears ----------------
// blockIdx.y: 0 -> q (pre-scaled 1/8) + qe[N,16], 1 -> k&v packed bf16, 2 -> skip

__global__ __launch_bounds__(256) void qkvs_kernel(
    const float* __restrict__ xin,
    const float* __restrict__ wqm, const float* __restrict__ bqm,
    const float* __restrict__ wkm, const float* __restrict__ bkm,
    const float* __restrict__ wvm, const float* __restrict__ bvm,
    const float* __restrict__ wsm, const float* __restrict__ bsm,
    const float* __restrict__ Aq, const float* __restrict__ beq,
    float* __restrict__ qo, uint32* __restrict__ kvo,
    float* __restrict__ so, float* __restrict__ qeo, int N)
{
    int mtx = blockIdx.y;
    __shared__ float W0[64][64];
    __shared__ float W1[64][64];
    __shared__ float X[64][64];
    __shared__ float As[64][17];
    int t = threadIdx.x;
    int col = t & 63;
    int sub = t >> 6;

    const float* w0 = (mtx == 0) ? wqm : (mtx == 1) ? wkm : wsm;
    const float* b0p = (mtx == 0) ? bqm : (mtx == 1) ? bkm : bsm;
    for (int r = t; r < 1024; r += 256) ((float4*)W0)[r] = ((const float4*)w0)[r];
    if (mtx == 1)
        for (int r = t; r < 1024; r += 256) ((float4*)W1)[r] = ((const float4*)wvm)[r];
    if (mtx == 0)
        for (int r = t; r < 1024; r += 256) As[r >> 4][r & 15] = Aq[r];
    int n0 = blockIdx.x * 64;
    if (n0 + 64 <= N) {
        const float4* xi4 = (const float4*)(xin + (size_t)n0 * 64);
        for (int r = t; r < 1024; r += 256) ((float4*)X)[r] = xi4[r];
    } else {
        for (int r = t; r < 4096; r += 256) {
            int n = n0 + (r >> 6);
            X[r >> 6][r & 63] = (n < N) ? xin[(size_t)n * 64 + (r & 63)] : 0.f;
        }
    }
    __syncthreads();

    float b0 = b0p[col];
    float b1 = (mtx == 1) ? bvm[col] : 0.f;

    for (int nb = sub * 16; nb < sub * 16 + 16; nb += 8) {
        float a0[8], a1[8];
        #pragma unroll
        for (int u = 0; u < 8; ++u) { a0[u] = b0; a1[u] = b1; }
        if (mtx == 1) {
            for (int j = 0; j < 64; ++j) {
                float wk_ = W0[j][col], wv_ = W1[j][col];
                #pragma unroll
                for (int u = 0; u < 8; ++u) {
                    float xv = X[nb + u][j];
                    a0[u] = fmaf(xv, wk_, a0[u]);
                    a1[u] = fmaf(xv, wv_, a1[u]);
                }
            }
        } else {
            for (int j = 0; j < 64; ++j) {
                float wj = W0[j][col];
                #pragma unroll
                for (int u = 0; u < 8; ++u) a0[u] = fmaf(X[nb + u][j], wj, a0[u]);
            }
        }
        #pragma unroll
        for (int u = 0; u < 8; ++u) {
            int n = n0 + nb + u;
            if (n < N) {
                if (mtx == 0)      qo[(size_t)n * 64 + col] = a0[u] * 0.125f;
                else if (mtx == 2) so[(size_t)n * 64 + col] = a0[u];
                else kvo[(size_t)n * 64 + col] = f2bf(a0[u]) | (f2bf(a1[u]) << 16);
            }
        }
    }

    if (mtx == 0) {
        #pragma unroll
        for (int rep = 0; rep < 4; ++rep) {
            int idx = rep * 256 + t;
            int n = idx >> 4, j = idx & 15;
            float acc = beq[j];
            for (int c = 0; c < 64; ++c) acc = fmaf(X[n][c], As[c][j], acc);
            int gn = n0 + n;
            if (gn < N) qeo[(size_t)gn * 16 + j] = acc;
        }
    }
}

// ---------------- per-node softmax aggregation (feature-blocked, 8 edges/iter) ------
// 4 waves/block, one wave per node. Lane (g,p): g=lane>>4 (edge slot), p=lane&15.
// Lane holds features 4p..4p+3. Per iteration: 8 edges via two independent
// score-reduce chains (ILP), two dwordx4 kv gathers/lane, two expf.

__global__ __launch_bounds__(256) void agg_kernel(
    const float* __restrict__ q, const uint32* __restrict__ kv,
    const float* __restrict__ qe, const float* __restrict__ we,
    const u16* __restrict__ ea16,
    const int* __restrict__ row_ptr, const int* __restrict__ csr_src,
    const float* __restrict__ skip_in, float* __restrict__ hout,
    const int* __restrict__ batch, float* __restrict__ pooled, int N)
{
    int lane = threadIdx.x & 63;
    int wid = (blockIdx.x << 2) + (threadIdx.x >> 6);
    if (wid >= N) return;
    int i = __builtin_amdgcn_readfirstlane(wid);

    int grp = lane >> 4;
    int pos = lane & 15;

    float4 qv = ((const float4*)(q + (size_t)i * 64))[pos];
    float qel = qe[(size_t)i * 16 + pos];
    float wer[16];
    #pragma unroll
    for (int j = 0; j < 16; ++j) wer[j] = we[j * 64 + lane];

    float den = 0.f, aj = 0.f;
    float o4x = 0.f, o4y = 0.f, o4z = 0.f, o4w = 0.f;

    int beg = row_ptr[i], end = row_ptr[i + 1];
    int last = end - 1;
    for (int p = beg; p < end; p += 8) {
        int egA = p + grp, egB = p + 4 + grp;
        int siA = (egA < end) ? egA : last;
        int siB = (egB < end) ? egB : last;
        int sA = csr_src[siA], sB = csr_src[siB];
        uint4 kbA = ((const uint4*)(kv + (size_t)sA * 64))[pos];
        uint4 kbB = ((const uint4*)(kv + (size_t)sB * 64))[pos];
        float eaA = bf2f(ea16[(size_t)p * 16 + lane]);
        float eaB = bf2f(ea16[(size_t)(p + 4) * 16 + lane]);

        float pa = eaA * qel, pb = eaB * qel;
        pa = fmaf(qv.x, __uint_as_float(kbA.x << 16), pa);
        pb = fmaf(qv.x, __uint_as_float(kbB.x << 16), pb);
        pa = fmaf(qv.y, __uint_as_float(kbA.y << 16), pa);
        pb = fmaf(qv.y, __uint_as_float(kbB.y << 16), pb);
        pa = fmaf(qv.z, __uint_as_float(kbA.z << 16), pa);
        pb = fmaf(qv.z, __uint_as_float(kbB.z << 16), pb);
        pa = fmaf(qv.w, __uint_as_float(kbA.w << 16), pa);
        pb = fmaf(qv.w, __uint_as_float(kbB.w << 16), pb);
        pa += __shfl_xor(pa, 1);  pb += __shfl_xor(pb, 1);
        pa += __shfl_xor(pa, 2);  pb += __shfl_xor(pb, 2);
        pa += __shfl_xor(pa, 4);  pb += __shfl_xor(pb, 4);
        pa += __shfl_xor(pa, 8);  pb += __shfl_xor(pb, 8);
        float scA = (egA < end) ? pa : -1e30f;
        float scB = (egB < end) ? pb : -1e30f;
        float wA = __expf(scA), wB = __expf(scB);

        den += wA + wB;
        aj = fmaf(wA, eaA, aj);
        aj = fmaf(wB, eaB, aj);
        o4x = fmaf(wA, __uint_as_float(kbA.x & 0xffff0000u), o4x);
        o4y = fmaf(wA, __uint_as_float(kbA.y & 0xffff0000u), o4y);
        o4z = fmaf(wA, __uint_as_float(kbA.z & 0xffff0000u), o4z);
        o4w = fmaf(wA, __uint_as_float(kbA.w & 0xffff0000u), o4w);
        o4x = fmaf(wB, __uint_as_float(kbB.x & 0xffff0000u), o4x);
        o4y = fmaf(wB, __uint_as_float(kbB.y & 0xffff0000u), o4y);
        o4z = fmaf(wB, __uint_as_float(kbB.z & 0xffff0000u), o4z);
        o4w = fmaf(wB, __uint_as_float(kbB.w & 0xffff0000u), o4w);
    }

    o4x += __shfl_xor(o4x, 16); o4x += __shfl_xor(o4x, 32);
    o4y += __shfl_xor(o4y, 16); o4y += __shfl_xor(o4y, 32);
    o4z += __shfl_xor(o4z, 16); o4z += __shfl_xor(o4z, 32);
    o4w += __shfl_xor(o4w, 16); o4w += __shfl_xor(o4w, 32);
    aj  += __shfl_xor(aj, 16);  aj  += __shfl_xor(aj, 32);
    den += __shfl_xor(den, 16); den += __shfl_xor(den, 32);

    int srcl = lane >> 2;
    float t0 = __shfl(o4x, srcl), t1 = __shfl(o4y, srcl);
    float t2 = __shfl(o4z, srcl), t3 = __shfl(o4w, srcl);
    int r2 = lane & 3;
    float o = (r2 == 0) ? t0 : (r2 == 1) ? t1 : (r2 == 2) ? t2 : t3;

    #pragma unroll
    for (int j = 0; j < 16; ++j) o = fmaf(__shfl(aj, j), wer[j], o);

    float dinv = (den > 0.f) ? 1.f / den : 0.f;
    float r = fmaf(o, dinv, skip_in[(size_t)i * 64 + lane]);
    r = (r >= 0.f) ? r : 0.01f * r;
    hout[(size_t)i * 64 + lane] = r;
    if (pooled) atomicAdd(&pooled[(size_t)batch[i] * 64 + lane], r);
}

// ---------------- head ----------------

__global__ void head_kernel(const float* __restrict__ pooled,
                            const float* __restrict__ w1, const float* __restrict__ b1,
                            const float* __restrict__ w2, const float* __restrict__ b2,
                            float* __restrict__ out, int G) {
    int g = blockIdx.x;
    int lane = threadIdx.x;
    __shared__ float hl[64];
    float p = pooled[g * 64 + lane];
    float ss = p * p;
    #pragma unroll
    for (int off = 32; off; off >>= 1) ss += __shfl_xor(ss, off);
    float hn = p / fmaxf(sqrtf(ss), 1e-12f);
    hl[lane] = hn;
    __syncthreads();
    float acc = b1[lane];
    #pragma unroll
    for (int j = 0; j < 64; ++j) acc = fmaf(hl[j], w1[j * 64 + lane], acc);
    acc = (acc >= 0.f) ? acc : 0.01f * acc;
    float r = acc * w2[lane];
    #pragma unroll
    for (int off = 32; off; off >>= 1) r += __shfl_xor(r, off);
    if (lane == 0) out[g] = r + b2[0];
}

// ---------------- launch ----------------

extern "C" void kernel_launch(void* const* d_in, const int* in_sizes, int n_in,
                              void* d_out, int out_size, void* d_ws, size_t ws_size,
                              hipStream_t stream) {
    const float* x     = (const float*)d_in[0];
    const int*   ei    = (const int*)  d_in[1];
    const float* ea    = (const float*)d_in[2];
    const int*   batch = (const int*)  d_in[3];
    const float *wq1=(const float*)d_in[4],  *bq1=(const float*)d_in[5];
    const float *wk1=(const float*)d_in[6],  *bk1=(const float*)d_in[7];
    const float *wv1=(const float*)d_in[8],  *bv1=(const float*)d_in[9];
    const float *we1=(const float*)d_in[10];
    const float *ws1=(const float*)d_in[11], *bs1=(const float*)d_in[12];
    const float *wq2=(const float*)d_in[13], *bq2=(const float*)d_in[14];
    const float *wk2=(const float*)d_in[15], *bk2=(const float*)d_in[16];
    const float *wv2=(const float*)d_in[17], *bv2=(const float*)d_in[18];
    const float *we2=(const float*)d_in[19];
    const float *ws2=(const float*)d_in[20], *bs2=(const float*)d_in[21];
    const float *wf1=(const float*)d_in[22], *bf1=(const float*)d_in[23];
    const float *wf2=(const float*)d_in[24], *bf2=(const float*)d_in[25];

    int N = in_sizes[0] / 64;
    int E = in_sizes[2] / 16;
    int G = out_size - N * 64;

    const int* srcA = ei;
    const int* dstA = ei + E;

    char* w = (char*)d_ws;
    float*  qb      = (float*)w;  w += (size_t)N * 64 * 4;
    uint32* kvb     = (uint32*)w; w += (size_t)N * 64 * 4;
    float*  hb      = (float*)w;  w += (size_t)N * 64 * 4;
    float*  qeb     = (float*)w;  w += (size_t)N * 16 * 4;
    float*  pooled  = (float*)w;  w += (size_t)G * 64 * 4;
    int* row_ptr    = (int*)w;    w += (size_t)(N + 1) * 4;
    int* totals     = (int*)w;    w += 256 * 4;
    float* A1       = (float*)w;  w += 1024 * 4;
    float* be1      = (float*)w;  w += 16 * 4;
    float* A2       = (float*)w;  w += 1024 * 4;
    float* be2      = (float*)w;  w += 16 * 4;
    int* csr_src    = (int*)w;    w += (size_t)E * 4;
    int* csr_eid    = (int*)w;    w += (size_t)E * 4;
    u16* ea16       = (u16*)w;    w += (size_t)(E * 16 + 128) * 2;
    int* deg  = (int*)qb;       // dead ranges of qb before qkvs writes it
    int* fill = (int*)qb + N;

    hipMemsetAsync(deg, 0, (size_t)2 * N * 4, stream);
    hipMemsetAsync(pooled, 0, (size_t)G * 64 * 4, stream);

    const int TB = 256;
    wqe_kernel<<<2, 256, 0, stream>>>(wq1, bq1, we1, wq2, bq2, we2, A1, be1, A2, be2);
    hist_kernel<<<(E + TB - 1) / TB, TB, 0, stream>>>(dstA, deg, E);
    int nb = (N + 1023) / 1024;
    scan1_kernel<<<nb, 1024, 0, stream>>>(deg, row_ptr, totals, N);
    scan2_kernel<<<1, 64, 0, stream>>>(totals, nb);
    scan3_kernel<<<(N + TB - 1) / TB, TB, 0, stream>>>(row_ptr, totals, N, E);
    scatter_kernel<<<(E + TB - 1) / TB, TB, 0, stream>>>(dstA, row_ptr, fill, csr_eid, E);
    convert_kernel<<<(E + TB - 1) / TB, TB, 0, stream>>>(csr_eid, srcA, ea,
                                                         csr_src, ea16, E);

    float* outp = (float*)d_out;
    float* atom = outp + G;

    dim3 qgrid((N + 63) / 64, 3);
    int aggBlocks = (N + 3) / 4;

    qkvs_kernel<<<qgrid, 256, 0, stream>>>(x, wq1, bq1, wk1, bk1, wv1, bv1, ws1, bs1,
                                           A1, be1, qb, kvb, hb, qeb, N);
    agg_kernel<<<aggBlocks, 256, 0, stream>>>(qb, kvb, qeb, we1, ea16, row_ptr, csr_src,
                                              hb, hb, nullptr, nullptr, N);

    qkvs_kernel<<<qgrid, 256, 0, stream>>>(hb, wq2, bq2, wk2, bk2, wv2, bv2, ws2, bs2,
                                           A2, be2, qb, kvb, atom, qeb, N);
    agg_kernel<<<aggBlocks, 256, 0, stream>>>(qb, kvb, qeb, we2, ea16, row_ptr, csr_src,
                                              atom, atom, batch, pooled, N);

    head_kernel<<<G, 64, 0, stream>>>(pooled, wf1, bf1, wf2, bf2, outp, G);
}

// Round 7
// 415.296 us; speedup vs baseline: 1.3146x; 1.0822x over previous
//
#include <hip/hip_runtime.h>
#include <hip/hip_bf16.h>
#include <math.h>

// UniMP 2-layer TransformerConv. N=50000, E=800000, G=512, D=64 (edge 16).
// R7: qkvs rebuilt on mfma_f32_16x16x32_bf16 with ZERO LDS: weight-prep kernel
// pre-transposes weights to bf16 B-frag layout (Wt[n][k]); A-frags loaded straight
// from global x (float4 -> bf16 pack). 34 MFMAs/wave cover q,k,v,skip,qe for 16
// nodes. Kills the 53.7KB LDS (25% occupancy) + 825k bank conflicts of R6 qkvs.

typedef unsigned int uint32;
typedef unsigned short u16;
typedef __attribute__((ext_vector_type(8))) short short8;
typedef __attribute__((ext_vector_type(4))) float f32x4;

__device__ __forceinline__ uint32 f2bf(float x) {
    uint32 u = __float_as_uint(x);
    u += 0x7fffu + ((u >> 16) & 1u);
    return u >> 16;
}
__device__ __forceinline__ float bf2f(u16 h) {
    return __uint_as_float(((uint32)h) << 16);
}

// ---------------- CSR build ----------------

__global__ void hist_kernel(const int* __restrict__ dst, int* __restrict__ deg, int E) {
    int e = blockIdx.x * blockDim.x + threadIdx.x;
    if (e < E) atomicAdd(&deg[dst[e]], 1);
}

__global__ void scan1_kernel(const int* __restrict__ deg, int* __restrict__ row_ptr,
                             int* __restrict__ totals, int N) {
    __shared__ int sh[1024];
    int tid = threadIdx.x;
    int i = blockIdx.x * 1024 + tid;
    int d = (i < N) ? deg[i] : 0;
    int val = d;
    sh[tid] = val;
    __syncthreads();
    for (int off = 1; off < 1024; off <<= 1) {
        int add = (tid >= off) ? sh[tid - off] : 0;
        __syncthreads();
        val += add;
        sh[tid] = val;
        __syncthreads();
    }
    if (i < N) row_ptr[i] = val - d;
    if (tid == 1023) totals[blockIdx.x] = val;
}

__global__ void scan2_kernel(int* totals, int nb) {
    int lane = threadIdx.x;
    int v = (lane < nb) ? totals[lane] : 0;
    #pragma unroll
    for (int off = 1; off < 64; off <<= 1) {
        int t = __shfl_up(v, off);
        if (lane >= off) v += t;
    }
    int ex = __shfl_up(v, 1);
    if (lane == 0) ex = 0;
    if (lane < nb) totals[lane] = ex;
}

__global__ void scan3_kernel(int* __restrict__ row_ptr, const int* __restrict__ totals,
                             int N, int E) {
    int i = blockIdx.x * blockDim.x + threadIdx.x;
    if (i < N) row_ptr[i] += totals[i >> 10];
    if (i == 0) row_ptr[N] = E;
}

__global__ void scatter_kernel(const int* __restrict__ dst, const int* __restrict__ row_ptr,
                               int* __restrict__ fill, int* __restrict__ csr_eid, int E) {
    int e = blockIdx.x * blockDim.x + threadIdx.x;
    if (e < E) {
        int d = dst[e];
        int pos = row_ptr[d] + atomicAdd(&fill[d], 1);
        csr_eid[pos] = e;
    }
}

__global__ void convert_kernel(const int* __restrict__ csr_eid, const int* __restrict__ src,
                               const float* __restrict__ ea,
                               int* __restrict__ csr_src, u16* __restrict__ ea16, int E) {
    int p = blockIdx.x * blockDim.x + threadIdx.x;
    if (p >= E) return;
    int e = csr_eid[p];
    csr_src[p] = src[e];
    const float4* ev = (const float4*)(ea + (size_t)e * 16);
    float4 q0 = ev[0], q1 = ev[1], q2 = ev[2], q3 = ev[3];
    uint32* o = (uint32*)(ea16 + (size_t)p * 16);
    o[0] = f2bf(q0.x) | (f2bf(q0.y) << 16);
    o[1] = f2bf(q0.z) | (f2bf(q0.w) << 16);
    o[2] = f2bf(q1.x) | (f2bf(q1.y) << 16);
    o[3] = f2bf(q1.z) | (f2bf(q1.w) << 16);
    o[4] = f2bf(q2.x) | (f2bf(q2.y) << 16);
    o[5] = f2bf(q2.z) | (f2bf(q2.w) << 16);
    o[6] = f2bf(q3.x) | (f2bf(q3.y) << 16);
    o[7] = f2bf(q3.z) | (f2bf(q3.w) << 16);
}

// ---------------- weight prep: transpose + bf16 for MFMA B-frags ----------------
// Wt[n][k] = W[k][n] (bf16). wta[j][k] = (Wq.We^T)[k][j]/8 (bf16). be[j] = (bq.We^T)[j]/8.
// grid 2: blockIdx.x = layer.

__global__ void wprep_kernel(
    const float* __restrict__ wq1, const float* __restrict__ bq1,
    const float* __restrict__ wk1, const float* __restrict__ wv1,
    const float* __restrict__ ws1, const float* __restrict__ we1,
    const float* __restrict__ wq2, const float* __restrict__ bq2,
    const float* __restrict__ wk2, const float* __restrict__ wv2,
    const float* __restrict__ ws2, const float* __restrict__ we2,
    u16* __restrict__ wt1, float* __restrict__ be1,
    u16* __restrict__ wt2, float* __restrict__ be2)
{
    int L = blockIdx.x;
    const float* wq = L ? wq2 : wq1;
    const float* bq = L ? bq2 : bq1;
    const float* wk = L ? wk2 : wk1;
    const float* wv = L ? wv2 : wv1;
    const float* ws = L ? ws2 : ws1;
    const float* we = L ? we2 : we1;
    u16* wt = L ? wt2 : wt1;           // [4*4096 main | 1024 wta]
    float* be = L ? be2 : be1;
    int t = threadIdx.x;
    for (int i = t; i < 4096; i += 256) {
        int k = i >> 6, n = i & 63;
        wt[0 * 4096 + n * 64 + k] = (u16)f2bf(wq[k * 64 + n]);
        wt[1 * 4096 + n * 64 + k] = (u16)f2bf(wk[k * 64 + n]);
        wt[2 * 4096 + n * 64 + k] = (u16)f2bf(wv[k * 64 + n]);
        wt[3 * 4096 + n * 64 + k] = (u16)f2bf(ws[k * 64 + n]);
    }
    for (int i = t; i < 1024; i += 256) {
        int j = i >> 6, k = i & 63;
        float acc = 0.f;
        for (int c = 0; c < 64; ++c) acc = fmaf(wq[k * 64 + c], we[j * 64 + c], acc);
        wt[4 * 4096 + j * 64 + k] = (u16)f2bf(acc * 0.125f);
    }
    if (t < 16) {
        float acc = 0.f;
        for (int c = 0; c < 64; ++c) acc = fmaf(bq[c], we[t * 64 + c], acc);
        be[t] = acc * 0.125f;
    }
}

// ---------------- MFMA fused node linears (no LDS) ----------------
// Block=256 (4 waves), 64 nodes/block; wave w owns nodes n0+w*16..+15.
// A-frag: lane(m=lane&15, k=quad*8+j) from x row; B-frags from pre-transposed wt.
// Outputs: q (pre-scaled 1/8), kv packed bf16, skip fp32, qe[N,16].

__global__ __launch_bounds__(256) void qkvs_mfma(
    const float* __restrict__ xin, const u16* __restrict__ wt,
    const float* __restrict__ bq, const float* __restrict__ bk,
    const float* __restrict__ bv, const float* __restrict__ bs,
    const float* __restrict__ be,
    float* __restrict__ qo, uint32* __restrict__ kvo,
    float* __restrict__ so, float* __restrict__ qeo, int N)
{
    int wave = threadIdx.x >> 6;
    int lane = threadIdx.x & 63;
    int quad = lane >> 4;
    int l16 = lane & 15;
    int n0 = blockIdx.x * 64 + wave * 16;
    int row = n0 + l16;
    int rn = (row < N) ? row : (N - 1);

    // A-frags: x[rn][quad*8..+7] and x[rn][32+quad*8..+7] as bf16x8
    const float4* xr = (const float4*)(xin + (size_t)rn * 64);
    float4 u0 = xr[quad * 2 + 0], u1 = xr[quad * 2 + 1];
    float4 u2 = xr[8 + quad * 2 + 0], u3 = xr[8 + quad * 2 + 1];
    short8 a0, a1;
    a0[0] = (short)f2bf(u0.x); a0[1] = (short)f2bf(u0.y);
    a0[2] = (short)f2bf(u0.z); a0[3] = (short)f2bf(u0.w);
    a0[4] = (short)f2bf(u1.x); a0[5] = (short)f2bf(u1.y);
    a0[6] = (short)f2bf(u1.z); a0[7] = (short)f2bf(u1.w);
    a1[0] = (short)f2bf(u2.x); a1[1] = (short)f2bf(u2.y);
    a1[2] = (short)f2bf(u2.z); a1[3] = (short)f2bf(u2.w);
    a1[4] = (short)f2bf(u3.x); a1[5] = (short)f2bf(u3.y);
    a1[6] = (short)f2bf(u3.z); a1[7] = (short)f2bf(u3.w);

    const short8* w8 = (const short8*)wt;   // [matrix*512 + n*8 + chunk]

    f32x4 acc[4][4];
    #pragma unroll
    for (int m = 0; m < 4; ++m)
        #pragma unroll
        for (int c = 0; c < 4; ++c) acc[m][c] = (f32x4){0.f, 0.f, 0.f, 0.f};
    f32x4 aqe = (f32x4){0.f, 0.f, 0.f, 0.f};

    #pragma unroll
    for (int m = 0; m < 4; ++m) {
        #pragma unroll
        for (int c = 0; c < 4; ++c) {
            short8 b0 = w8[m * 512 + (c * 16 + l16) * 8 + quad];
            short8 b1 = w8[m * 512 + (c * 16 + l16) * 8 + 4 + quad];
            acc[m][c] = __builtin_amdgcn_mfma_f32_16x16x32_bf16(a0, b0, acc[m][c], 0, 0, 0);
            acc[m][c] = __builtin_amdgcn_mfma_f32_16x16x32_bf16(a1, b1, acc[m][c], 0, 0, 0);
        }
    }
    {
        short8 b0 = w8[4 * 512 + l16 * 8 + quad];
        short8 b1 = w8[4 * 512 + l16 * 8 + 4 + quad];
        aqe = __builtin_amdgcn_mfma_f32_16x16x32_bf16(a0, b0, aqe, 0, 0, 0);
        aqe = __builtin_amdgcn_mfma_f32_16x16x32_bf16(a1, b1, aqe, 0, 0, 0);
    }

    // epilogue: C layout row=quad*4+r, col=c*16+l16
    int node0 = n0 + quad * 4;
    #pragma unroll
    for (int c = 0; c < 4; ++c) {
        int col = c * 16 + l16;
        float bQ = bq[col], bK = bk[col], bV = bv[col], bS = bs[col];
        #pragma unroll
        for (int r = 0; r < 4; ++r) {
            int node = node0 + r;
            if (node < N) {
                size_t off = (size_t)node * 64 + col;
                qo[off] = (acc[0][c][r] + bQ) * 0.125f;
                kvo[off] = f2bf(acc[1][c][r] + bK) | (f2bf(acc[2][c][r] + bV) << 16);
                so[off] = acc[3][c][r] + bS;
            }
        }
    }
    float beL = be[l16];
    #pragma unroll
    for (int r = 0; r < 4; ++r) {
        int node = node0 + r;
        if (node < N) qeo[(size_t)node * 16 + l16] = aqe[r] + beL;
    }
}

// ---------------- per-node softmax aggregation (feature-blocked, 8 edges/iter) ------

__global__ __launch_bounds__(256) void agg_kernel(
    const float* __restrict__ q, const uint32* __restrict__ kv,
    const float* __restrict__ qe, const float* __restrict__ we,
    const u16* __restrict__ ea16,
    const int* __restrict__ row_ptr, const int* __restrict__ csr_src,
    const float* __restrict__ skip_in, float* __restrict__ hout,
    const int* __restrict__ batch, float* __restrict__ pooled, int N)
{
    int lane = threadIdx.x & 63;
    int wid = (blockIdx.x << 2) + (threadIdx.x >> 6);
    if (wid >= N) return;
    int i = __builtin_amdgcn_readfirstlane(wid);

    int grp = lane >> 4;
    int pos = lane & 15;

    float4 qv = ((const float4*)(q + (size_t)i * 64))[pos];
    float qel = qe[(size_t)i * 16 + pos];
    float wer[16];
    #pragma unroll
    for (int j = 0; j < 16; ++j) wer[j] = we[j * 64 + lane];

    float den = 0.f, aj = 0.f;
    float o4x = 0.f, o4y = 0.f, o4z = 0.f, o4w = 0.f;

    int beg = row_ptr[i], end = row_ptr[i + 1];
    int last = end - 1;
    for (int p = beg; p < end; p += 8) {
        int egA = p + grp, egB = p + 4 + grp;
        int siA = (egA < end) ? egA : last;
        int siB = (egB < end) ? egB : last;
        int sA = csr_src[siA], sB = csr_src[siB];
        uint4 kbA = ((const uint4*)(kv + (size_t)sA * 64))[pos];
        uint4 kbB = ((const uint4*)(kv + (size_t)sB * 64))[pos];
        float eaA = bf2f(ea16[(size_t)p * 16 + lane]);
        float eaB = bf2f(ea16[(size_t)(p + 4) * 16 + lane]);

        float pa = eaA * qel, pb = eaB * qel;
        pa = fmaf(qv.x, __uint_as_float(kbA.x << 16), pa);
        pb = fmaf(qv.x, __uint_as_float(kbB.x << 16), pb);
        pa = fmaf(qv.y, __uint_as_float(kbA.y << 16), pa);
        pb = fmaf(qv.y, __uint_as_float(kbB.y << 16), pb);
        pa = fmaf(qv.z, __uint_as_float(kbA.z << 16), pa);
        pb = fmaf(qv.z, __uint_as_float(kbB.z << 16), pb);
        pa = fmaf(qv.w, __uint_as_float(kbA.w << 16), pa);
        pb = fmaf(qv.w, __uint_as_float(kbB.w << 16), pb);
        pa += __shfl_xor(pa, 1);  pb += __shfl_xor(pb, 1);
        pa += __shfl_xor(pa, 2);  pb += __shfl_xor(pb, 2);
        pa += __shfl_xor(pa, 4);  pb += __shfl_xor(pb, 4);
        pa += __shfl_xor(pa, 8);  pb += __shfl_xor(pb, 8);
        float scA = (egA < end) ? pa : -1e30f;
        float scB = (egB < end) ? pb : -1e30f;
        float wA = __expf(scA), wB = __expf(scB);

        den += wA + wB;
        aj = fmaf(wA, eaA, aj);
        aj = fmaf(wB, eaB, aj);
        o4x = fmaf(wA, __uint_as_float(kbA.x & 0xffff0000u), o4x);
        o4y = fmaf(wA, __uint_as_float(kbA.y & 0xffff0000u), o4y);
        o4z = fmaf(wA, __uint_as_float(kbA.z & 0xffff0000u), o4z);
        o4w = fmaf(wA, __uint_as_float(kbA.w & 0xffff0000u), o4w);
        o4x = fmaf(wB, __uint_as_float(kbB.x & 0xffff0000u), o4x);
        o4y = fmaf(wB, __uint_as_float(kbB.y & 0xffff0000u), o4y);
        o4z = fmaf(wB, __uint_as_float(kbB.z & 0xffff0000u), o4z);
        o4w = fmaf(wB, __uint_as_float(kbB.w & 0xffff0000u), o4w);
    }

    o4x += __shfl_xor(o4x, 16); o4x += __shfl_xor(o4x, 32);
    o4y += __shfl_xor(o4y, 16); o4y += __shfl_xor(o4y, 32);
    o4z += __shfl_xor(o4z, 16); o4z += __shfl_xor(o4z, 32);
    o4w += __shfl_xor(o4w, 16); o4w += __shfl_xor(o4w, 32);
    aj  += __shfl_xor(aj, 16);  aj  += __shfl_xor(aj, 32);
    den += __shfl_xor(den, 16); den += __shfl_xor(den, 32);

    int srcl = lane >> 2;
    float t0 = __shfl(o4x, srcl), t1 = __shfl(o4y, srcl);
    float t2 = __shfl(o4z, srcl), t3 = __shfl(o4w, srcl);
    int r2 = lane & 3;
    float o = (r2 == 0) ? t0 : (r2 == 1) ? t1 : (r2 == 2) ? t2 : t3;

    #pragma unroll
    for (int j = 0; j < 16; ++j) o = fmaf(__shfl(aj, j), wer[j], o);

    float dinv = (den > 0.f) ? 1.f / den : 0.f;
    float r = fmaf(o, dinv, skip_in[(size_t)i * 64 + lane]);
    r = (r >= 0.f) ? r : 0.01f * r;
    hout[(size_t)i * 64 + lane] = r;
    if (pooled) atomicAdd(&pooled[(size_t)batch[i] * 64 + lane], r);
}

// ---------------- head ----------------

__global__ void head_kernel(const float* __restrict__ pooled,
                            const float* __restrict__ w1, const float* __restrict__ b1,
                            const float* __restrict__ w2, const float* __restrict__ b2,
                            float* __restrict__ out, int G) {
    int g = blockIdx.x;
    int lane = threadIdx.x;
    __shared__ float hl[64];
    float p = pooled[g * 64 + lane];
    float ss = p * p;
    #pragma unroll
    for (int off = 32; off; off >>= 1) ss += __shfl_xor(ss, off);
    float hn = p / fmaxf(sqrtf(ss), 1e-12f);
    hl[lane] = hn;
    __syncthreads();
    float acc = b1[lane];
    #pragma unroll
    for (int j = 0; j < 64; ++j) acc = fmaf(hl[j], w1[j * 64 + lane], acc);
    acc = (acc >= 0.f) ? acc : 0.01f * acc;
    float r = acc * w2[lane];
    #pragma unroll
    for (int off = 32; off; off >>= 1) r += __shfl_xor(r, off);
    if (lane == 0) out[g] = r + b2[0];
}

// ---------------- launch ----------------

extern "C" void kernel_launch(void* const* d_in, const int* in_sizes, int n_in,
                              void* d_out, int out_size, void* d_ws, size_t ws_size,
                              hipStream_t stream) {
    const float* x     = (const float*)d_in[0];
    const int*   ei    = (const int*)  d_in[1];
    const float* ea    = (const float*)d_in[2];
    const int*   batch = (const int*)  d_in[3];
    const float *wq1=(const float*)d_in[4],  *bq1=(const float*)d_in[5];
    const float *wk1=(const float*)d_in[6],  *bk1=(const float*)d_in[7];
    const float *wv1=(const float*)d_in[8],  *bv1=(const float*)d_in[9];
    const float *we1=(const float*)d_in[10];
    const float *ws1=(const float*)d_in[11], *bs1=(const float*)d_in[12];
    const float *wq2=(const float*)d_in[13], *bq2=(const float*)d_in[14];
    const float *wk2=(const float*)d_in[15], *bk2=(const float*)d_in[16];
    const float *wv2=(const float*)d_in[17], *bv2=(const float*)d_in[18];
    const float *we2=(const float*)d_in[19];
    const float *ws2=(const float*)d_in[20], *bs2=(const float*)d_in[21];
    const float *wf1=(const float*)d_in[22], *bf1=(const float*)d_in[23];
    const float *wf2=(const float*)d_in[24], *bf2=(const float*)d_in[25];

    int N = in_sizes[0] / 64;
    int E = in_sizes[2] / 16;
    int G = out_size - N * 64;

    const int* srcA = ei;
    const int* dstA = ei + E;

    char* w = (char*)d_ws;
    float*  qb      = (float*)w;  w += (size_t)N * 64 * 4;
    uint32* kvb     = (uint32*)w; w += (size_t)N * 64 * 4;
    float*  hb      = (float*)w;  w += (size_t)N * 64 * 4;
    float*  qeb     = (float*)w;  w += (size_t)N * 16 * 4;
    float*  pooled  = (float*)w;  w += (size_t)G * 64 * 4;
    int* row_ptr    = (int*)w;    w += (size_t)(N + 1) * 4;
    int* totals     = (int*)w;    w += 256 * 4;
    u16* wt1        = (u16*)w;    w += (4 * 4096 + 1024) * 2;
    u16* wt2        = (u16*)w;    w += (4 * 4096 + 1024) * 2;
    float* be1      = (float*)w;  w += 16 * 4;
    float* be2      = (float*)w;  w += 16 * 4;
    int* csr_src    = (int*)w;    w += (size_t)E * 4;
    int* csr_eid    = (int*)w;    w += (size_t)E * 4;
    u16* ea16       = (u16*)w;    w += (size_t)(E * 16 + 128) * 2;
    int* deg  = (int*)qb;       // dead ranges of qb before qkvs writes it
    int* fill = (int*)qb + N;

    hipMemsetAsync(deg, 0, (size_t)2 * N * 4, stream);
    hipMemsetAsync(pooled, 0, (size_t)G * 64 * 4, stream);

    const int TB = 256;
    wprep_kernel<<<2, 256, 0, stream>>>(wq1, bq1, wk1, wv1, ws1, we1,
                                        wq2, bq2, wk2, wv2, ws2, we2,
                                        wt1, be1, wt2, be2);
    hist_kernel<<<(E + TB - 1) / TB, TB, 0, stream>>>(dstA, deg, E);
    int nb = (N + 1023) / 1024;
    scan1_kernel<<<nb, 1024, 0, stream>>>(deg, row_ptr, totals, N);
    scan2_kernel<<<1, 64, 0, stream>>>(totals, nb);
    scan3_kernel<<<(N + TB - 1) / TB, TB, 0, stream>>>(row_ptr, totals, N, E);
    scatter_kernel<<<(E + TB - 1) / TB, TB, 0, stream>>>(dstA, row_ptr, fill, csr_eid, E);
    convert_kernel<<<(E + TB - 1) / TB, TB, 0, stream>>>(csr_eid, srcA, ea,
                                                         csr_src, ea16, E);

    float* outp = (float*)d_out;
    float* atom = outp + G;

    int qBlocks = (N + 63) / 64;
    int aggBlocks = (N + 3) / 4;

    qkvs_mfma<<<qBlocks, 256, 0, stream>>>(x, wt1, bq1, bk1, bv1, bs1, be1,
                                           qb, kvb, hb, qeb, N);
    agg_kernel<<<aggBlocks, 256, 0, stream>>>(qb, kvb, qeb, we1, ea16, row_ptr, csr_src,
                                              hb, hb, nullptr, nullptr, N);

    qkvs_mfma<<<qBlocks, 256, 0, stream>>>(hb, wt2, bq2, bk2, bv2, bs2, be2,
                                           qb, kvb, atom, qeb, N);
    agg_kernel<<<aggBlocks, 256, 0, stream>>>(qb, kvb, qeb, we2, ea16, row_ptr, csr_src,
                                              atom, atom, batch, pooled, N);

    head_kernel<<<G, 64, 0, stream>>>(pooled, wf1, bf1, wf2, bf2, outp, G);
}

// Round 8
// 381.007 us; speedup vs baseline: 1.4329x; 1.0900x over previous
//
#include <hip/hip_runtime.h>
#include <hip/hip_bf16.h>
#include <math.h>

// UniMP 2-layer TransformerConv. N=50000, E=800000, G=512, D=64 (edge 16).
// R8: bucketed CSR build (dense writes only): bucket_append (LDS counting-sort
// partition, per-block range reservation -> sequential 8B appends), csr_index
// (per-bucket rowptr + slot->CSR pos, all coalesced), csr_fill (slot-parallel ea
// gather, dense region writes). Replaces hist/scan1/2/3/scatter/convert.
// agg: 16 edges/iter, 4 independent score-reduce chains.

typedef unsigned int uint32;
typedef unsigned short u16;
typedef __attribute__((ext_vector_type(8))) short short8;
typedef __attribute__((ext_vector_type(4))) float f32x4;

#define BW 256        // dsts per bucket
#define CAP 5120      // max edges per bucket (mean 4081, +16 sigma)
#define EPB 2048      // edges per block in bucket_append

__device__ __forceinline__ uint32 f2bf(float x) {
    uint32 u = __float_as_uint(x);
    u += 0x7fffu + ((u >> 16) & 1u);
    return u >> 16;
}
__device__ __forceinline__ float bf2f(u16 h) {
    return __uint_as_float(((uint32)h) << 16);
}

// ---------------- bucketed CSR build ----------------

__global__ __launch_bounds__(256) void bucket_append(
    const int* __restrict__ dst, const int* __restrict__ src,
    int* __restrict__ bcount, uint2* __restrict__ buf, int E, int NB)
{
    __shared__ int hist[256], gbase[256], fill[256];
    int t = threadIdx.x;
    hist[t] = 0; fill[t] = 0;
    __syncthreads();
    int e0 = blockIdx.x * EPB;
    int d[8], s[8];
    #pragma unroll
    for (int k = 0; k < 8; ++k) {
        int e = e0 + k * 256 + t;
        if (e < E) {
            d[k] = dst[e]; s[k] = src[e];
            atomicAdd(&hist[d[k] >> 8], 1);
        } else d[k] = -1;
    }
    __syncthreads();
    if (t < NB && hist[t] > 0) gbase[t] = atomicAdd(&bcount[t], hist[t]);
    __syncthreads();
    #pragma unroll
    for (int k = 0; k < 8; ++k) {
        if (d[k] >= 0) {
            int e = e0 + k * 256 + t;
            int b = d[k] >> 8;
            int off = atomicAdd(&fill[b], 1);
            buf[(size_t)b * CAP + gbase[b] + off] =
                make_uint2(((uint32)(d[k] & 255) << 20) | (uint32)e, (uint32)s[k]);
        }
    }
}

// one block per bucket: row_ptr for its dst range + global CSR pos per slot
__global__ __launch_bounds__(256) void csr_index(
    const int* __restrict__ bcount, const uint2* __restrict__ buf,
    int* __restrict__ row_ptr, int* __restrict__ gpos, int N, int E, int NB)
{
    __shared__ int sc[256], lh[256], lo[256], fill[256];
    int t = threadIdx.x;
    int b = blockIdx.x;
    sc[t] = (t < NB) ? bcount[t] : 0;
    lh[t] = 0; fill[t] = 0;
    __syncthreads();
    for (int off = 1; off < 256; off <<= 1) {
        int add = (t >= off) ? sc[t - off] : 0;
        __syncthreads();
        sc[t] += add;
        __syncthreads();
    }
    int cnt = bcount[b];
    int base = sc[b] - cnt;            // exclusive prefix = bucket base in CSR

    const uint2* bb = buf + (size_t)b * CAP;
    for (int i = t; i < cnt; i += 256) atomicAdd(&lh[(int)(bb[i].x >> 20)], 1);
    __syncthreads();
    int v = lh[t];
    lo[t] = v;
    __syncthreads();
    for (int off = 1; off < 256; off <<= 1) {
        int add = (t >= off) ? lo[t - off] : 0;
        __syncthreads();
        lo[t] += add;
        __syncthreads();
    }
    int ex = lo[t] - v;                // exclusive local offset for dst (b*BW+t)
    int d = b * BW + t;
    if (d < N) row_ptr[d] = base + ex;
    if (b == 0 && t == 0) row_ptr[N] = E;
    lo[t] = ex;                        // own-slot overwrite, then barrier
    __syncthreads();
    for (int i = t; i < cnt; i += 256) {
        int dl = (int)(bb[i].x >> 20);
        int off = atomicAdd(&fill[dl], 1);
        gpos[(size_t)b * CAP + i] = base + lo[dl] + off;
    }
}

// slot-parallel: gather ea row, write csr_src + bf16 ea16 dense per bucket region
__global__ __launch_bounds__(256) void csr_fill(
    const int* __restrict__ bcount, const uint2* __restrict__ buf,
    const int* __restrict__ gpos, const float* __restrict__ ea,
    int* __restrict__ csr_src, u16* __restrict__ ea16)
{
    int b = blockIdx.y;
    int slot = blockIdx.x * 256 + threadIdx.x;
    if (slot >= bcount[b]) return;
    size_t idx = (size_t)b * CAP + slot;
    uint2 ent = buf[idx];
    int gp = gpos[idx];
    csr_src[gp] = (int)ent.y;
    int e = (int)(ent.x & 0xFFFFFu);
    const float4* ev = (const float4*)(ea + (size_t)e * 16);
    float4 q0 = ev[0], q1 = ev[1], q2 = ev[2], q3 = ev[3];
    uint32* o = (uint32*)(ea16 + (size_t)gp * 16);
    o[0] = f2bf(q0.x) | (f2bf(q0.y) << 16);
    o[1] = f2bf(q0.z) | (f2bf(q0.w) << 16);
    o[2] = f2bf(q1.x) | (f2bf(q1.y) << 16);
    o[3] = f2bf(q1.z) | (f2bf(q1.w) << 16);
    o[4] = f2bf(q2.x) | (f2bf(q2.y) << 16);
    o[5] = f2bf(q2.z) | (f2bf(q2.w) << 16);
    o[6] = f2bf(q3.x) | (f2bf(q3.y) << 16);
    o[7] = f2bf(q3.z) | (f2bf(q3.w) << 16);
}

// ---------------- weight prep: transpose + bf16 for MFMA B-frags ----------------

__global__ void wprep_kernel(
    const float* __restrict__ wq1, const float* __restrict__ bq1,
    const float* __restrict__ wk1, const float* __restrict__ wv1,
    const float* __restrict__ ws1, const float* __restrict__ we1,
    const float* __restrict__ wq2, const float* __restrict__ bq2,
    const float* __restrict__ wk2, const float* __restrict__ wv2,
    const float* __restrict__ ws2, const float* __restrict__ we2,
    u16* __restrict__ wt1, float* __restrict__ be1,
    u16* __restrict__ wt2, float* __restrict__ be2)
{
    int L = blockIdx.x;
    const float* wq = L ? wq2 : wq1;
    const float* bq = L ? bq2 : bq1;
    const float* wk = L ? wk2 : wk1;
    const float* wv = L ? wv2 : wv1;
    const float* ws = L ? ws2 : ws1;
    const float* we = L ? we2 : we1;
    u16* wt = L ? wt2 : wt1;
    float* be = L ? be2 : be1;
    int t = threadIdx.x;
    for (int i = t; i < 4096; i += 256) {
        int k = i >> 6, n = i & 63;
        wt[0 * 4096 + n * 64 + k] = (u16)f2bf(wq[k * 64 + n]);
        wt[1 * 4096 + n * 64 + k] = (u16)f2bf(wk[k * 64 + n]);
        wt[2 * 4096 + n * 64 + k] = (u16)f2bf(wv[k * 64 + n]);
        wt[3 * 4096 + n * 64 + k] = (u16)f2bf(ws[k * 64 + n]);
    }
    for (int i = t; i < 1024; i += 256) {
        int j = i >> 6, k = i & 63;
        float acc = 0.f;
        for (int c = 0; c < 64; ++c) acc = fmaf(wq[k * 64 + c], we[j * 64 + c], acc);
        wt[4 * 4096 + j * 64 + k] = (u16)f2bf(acc * 0.125f);
    }
    if (t < 16) {
        float acc = 0.f;
        for (int c = 0; c < 64; ++c) acc = fmaf(bq[c], we[t * 64 + c], acc);
        be[t] = acc * 0.125f;
    }
}

// ---------------- MFMA fused node linears (no LDS) ----------------

__global__ __launch_bounds__(256) void qkvs_mfma(
    const float* __restrict__ xin, const u16* __restrict__ wt,
    const float* __restrict__ bq, const float* __restrict__ bk,
    const float* __restrict__ bv, const float* __restrict__ bs,
    const float* __restrict__ be,
    float* __restrict__ qo, uint32* __restrict__ kvo,
    float* __restrict__ so, float* __restrict__ qeo, int N)
{
    int wave = threadIdx.x >> 6;
    int lane = threadIdx.x & 63;
    int quad = lane >> 4;
    int l16 = lane & 15;
    int n0 = blockIdx.x * 64 + wave * 16;
    int row = n0 + l16;
    int rn = (row < N) ? row : (N - 1);

    const float4* xr = (const float4*)(xin + (size_t)rn * 64);
    float4 u0 = xr[quad * 2 + 0], u1 = xr[quad * 2 + 1];
    float4 u2 = xr[8 + quad * 2 + 0], u3 = xr[8 + quad * 2 + 1];
    short8 a0, a1;
    a0[0] = (short)f2bf(u0.x); a0[1] = (short)f2bf(u0.y);
    a0[2] = (short)f2bf(u0.z); a0[3] = (short)f2bf(u0.w);
    a0[4] = (short)f2bf(u1.x); a0[5] = (short)f2bf(u1.y);
    a0[6] = (short)f2bf(u1.z); a0[7] = (short)f2bf(u1.w);
    a1[0] = (short)f2bf(u2.x); a1[1] = (short)f2bf(u2.y);
    a1[2] = (short)f2bf(u2.z); a1[3] = (short)f2bf(u2.w);
    a1[4] = (short)f2bf(u3.x); a1[5] = (short)f2bf(u3.y);
    a1[6] = (short)f2bf(u3.z); a1[7] = (short)f2bf(u3.w);

    const short8* w8 = (const short8*)wt;

    f32x4 acc[4][4];
    #pragma unroll
    for (int m = 0; m < 4; ++m)
        #pragma unroll
        for (int c = 0; c < 4; ++c) acc[m][c] = (f32x4){0.f, 0.f, 0.f, 0.f};
    f32x4 aqe = (f32x4){0.f, 0.f, 0.f, 0.f};

    #pragma unroll
    for (int m = 0; m < 4; ++m) {
        #pragma unroll
        for (int c = 0; c < 4; ++c) {
            short8 b0 = w8[m * 512 + (c * 16 + l16) * 8 + quad];
            short8 b1 = w8[m * 512 + (c * 16 + l16) * 8 + 4 + quad];
            acc[m][c] = __builtin_amdgcn_mfma_f32_16x16x32_bf16(a0, b0, acc[m][c], 0, 0, 0);
            acc[m][c] = __builtin_amdgcn_mfma_f32_16x16x32_bf16(a1, b1, acc[m][c], 0, 0, 0);
        }
    }
    {
        short8 b0 = w8[4 * 512 + l16 * 8 + quad];
        short8 b1 = w8[4 * 512 + l16 * 8 + 4 + quad];
        aqe = __builtin_amdgcn_mfma_f32_16x16x32_bf16(a0, b0, aqe, 0, 0, 0);
        aqe = __builtin_amdgcn_mfma_f32_16x16x32_bf16(a1, b1, aqe, 0, 0, 0);
    }

    int node0 = n0 + quad * 4;
    #pragma unroll
    for (int c = 0; c < 4; ++c) {
        int col = c * 16 + l16;
        float bQ = bq[col], bK = bk[col], bV = bv[col], bS = bs[col];
        #pragma unroll
        for (int r = 0; r < 4; ++r) {
            int node = node0 + r;
            if (node < N) {
                size_t off = (size_t)node * 64 + col;
                qo[off] = (acc[0][c][r] + bQ) * 0.125f;
                kvo[off] = f2bf(acc[1][c][r] + bK) | (f2bf(acc[2][c][r] + bV) << 16);
                so[off] = acc[3][c][r] + bS;
            }
        }
    }
    float beL = be[l16];
    #pragma unroll
    for (int r = 0; r < 4; ++r) {
        int node = node0 + r;
        if (node < N) qeo[(size_t)node * 16 + l16] = aqe[r] + beL;
    }
}

// ---------------- per-node softmax aggregation (feature-blocked, 16 edges/iter) -----

__global__ __launch_bounds__(256) void agg_kernel(
    const float* __restrict__ q, const uint32* __restrict__ kv,
    const float* __restrict__ qe, const float* __restrict__ we,
    const u16* __restrict__ ea16,
    const int* __restrict__ row_ptr, const int* __restrict__ csr_src,
    const float* __restrict__ skip_in, float* __restrict__ hout,
    const int* __restrict__ batch, float* __restrict__ pooled, int N)
{
    int lane = threadIdx.x & 63;
    int wid = (blockIdx.x << 2) + (threadIdx.x >> 6);
    if (wid >= N) return;
    int i = __builtin_amdgcn_readfirstlane(wid);

    int grp = lane >> 4;
    int pos = lane & 15;

    float4 qv = ((const float4*)(q + (size_t)i * 64))[pos];
    float qel = qe[(size_t)i * 16 + pos];
    float wer[16];
    #pragma unroll
    for (int j = 0; j < 16; ++j) wer[j] = we[j * 64 + lane];

    float den = 0.f, aj = 0.f;
    float o4x = 0.f, o4y = 0.f, o4z = 0.f, o4w = 0.f;

    int beg = row_ptr[i], end = row_ptr[i + 1];
    int last = end - 1;
    for (int p = beg; p < end; p += 16) {
        #pragma unroll
        for (int c = 0; c < 4; ++c) {
            int eg = p + 4 * c + grp;
            int si = (eg < end) ? eg : last;
            int s = csr_src[si];
            uint4 kb = ((const uint4*)(kv + (size_t)s * 64))[pos];
            float eav = bf2f(ea16[(size_t)(p + 4 * c) * 16 + lane]);
            float pa = eav * qel;
            pa = fmaf(qv.x, __uint_as_float(kb.x << 16), pa);
            pa = fmaf(qv.y, __uint_as_float(kb.y << 16), pa);
            pa = fmaf(qv.z, __uint_as_float(kb.z << 16), pa);
            pa = fmaf(qv.w, __uint_as_float(kb.w << 16), pa);
            pa += __shfl_xor(pa, 1);
            pa += __shfl_xor(pa, 2);
            pa += __shfl_xor(pa, 4);
            pa += __shfl_xor(pa, 8);
            float sc = (eg < end) ? pa : -1e30f;
            float w = __expf(sc);
            den += w;
            aj = fmaf(w, eav, aj);
            o4x = fmaf(w, __uint_as_float(kb.x & 0xffff0000u), o4x);
            o4y = fmaf(w, __uint_as_float(kb.y & 0xffff0000u), o4y);
            o4z = fmaf(w, __uint_as_float(kb.z & 0xffff0000u), o4z);
            o4w = fmaf(w, __uint_as_float(kb.w & 0xffff0000u), o4w);
        }
    }

    o4x += __shfl_xor(o4x, 16); o4x += __shfl_xor(o4x, 32);
    o4y += __shfl_xor(o4y, 16); o4y += __shfl_xor(o4y, 32);
    o4z += __shfl_xor(o4z, 16); o4z += __shfl_xor(o4z, 32);
    o4w += __shfl_xor(o4w, 16); o4w += __shfl_xor(o4w, 32);
    aj  += __shfl_xor(aj, 16);  aj  += __shfl_xor(aj, 32);
    den += __shfl_xor(den, 16); den += __shfl_xor(den, 32);

    int srcl = lane >> 2;
    float t0 = __shfl(o4x, srcl), t1 = __shfl(o4y, srcl);
    float t2 = __shfl(o4z, srcl), t3 = __shfl(o4w, srcl);
    int r2 = lane & 3;
    float o = (r2 == 0) ? t0 : (r2 == 1) ? t1 : (r2 == 2) ? t2 : t3;

    #pragma unroll
    for (int j = 0; j < 16; ++j) o = fmaf(__shfl(aj, j), wer[j], o);

    float dinv = (den > 0.f) ? 1.f / den : 0.f;
    float r = fmaf(o, dinv, skip_in[(size_t)i * 64 + lane]);
    r = (r >= 0.f) ? r : 0.01f * r;
    hout[(size_t)i * 64 + lane] = r;
    if (pooled) atomicAdd(&pooled[(size_t)batch[i] * 64 + lane], r);
}

// ---------------- head ----------------

__global__ void head_kernel(const float* __restrict__ pooled,
                            const float* __restrict__ w1, const float* __restrict__ b1,
                            const float* __restrict__ w2, const float* __restrict__ b2,
                            float* __restrict__ out, int G) {
    int g = blockIdx.x;
    int lane = threadIdx.x;
    __shared__ float hl[64];
    float p = pooled[g * 64 + lane];
    float ss = p * p;
    #pragma unroll
    for (int off = 32; off; off >>= 1) ss += __shfl_xor(ss, off);
    float hn = p / fmaxf(sqrtf(ss), 1e-12f);
    hl[lane] = hn;
    __syncthreads();
    float acc = b1[lane];
    #pragma unroll
    for (int j = 0; j < 64; ++j) acc = fmaf(hl[j], w1[j * 64 + lane], acc);
    acc = (acc >= 0.f) ? acc : 0.01f * acc;
    float r = acc * w2[lane];
    #pragma unroll
    for (int off = 32; off; off >>= 1) r += __shfl_xor(r, off);
    if (lane == 0) out[g] = r + b2[0];
}

// ---------------- launch ----------------

extern "C" void kernel_launch(void* const* d_in, const int* in_sizes, int n_in,
                              void* d_out, int out_size, void* d_ws, size_t ws_size,
                              hipStream_t stream) {
    const float* x     = (const float*)d_in[0];
    const int*   ei    = (const int*)  d_in[1];
    const float* ea    = (const float*)d_in[2];
    const int*   batch = (const int*)  d_in[3];
    const float *wq1=(const float*)d_in[4],  *bq1=(const float*)d_in[5];
    const float *wk1=(const float*)d_in[6],  *bk1=(const float*)d_in[7];
    const float *wv1=(const float*)d_in[8],  *bv1=(const float*)d_in[9];
    const float *we1=(const float*)d_in[10];
    const float *ws1=(const float*)d_in[11], *bs1=(const float*)d_in[12];
    const float *wq2=(const float*)d_in[13], *bq2=(const float*)d_in[14];
    const float *wk2=(const float*)d_in[15], *bk2=(const float*)d_in[16];
    const float *wv2=(const float*)d_in[17], *bv2=(const float*)d_in[18];
    const float *we2=(const float*)d_in[19];
    const float *ws2=(const float*)d_in[20], *bs2=(const float*)d_in[21];
    const float *wf1=(const float*)d_in[22], *bf1=(const float*)d_in[23];
    const float *wf2=(const float*)d_in[24], *bf2=(const float*)d_in[25];

    int N = in_sizes[0] / 64;
    int E = in_sizes[2] / 16;
    int G = out_size - N * 64;
    int NB = (N + BW - 1) / BW;

    const int* srcA = ei;
    const int* dstA = ei + E;

    char* w = (char*)d_ws;
    float*  qb      = (float*)w;  w += (size_t)N * 64 * 4;
    uint32* kvb     = (uint32*)w; w += (size_t)N * 64 * 4;
    float*  hb      = (float*)w;  w += (size_t)N * 64 * 4;
    float*  qeb     = (float*)w;  w += (size_t)N * 16 * 4;
    float*  pooled  = (float*)w;  w += (size_t)G * 64 * 4;
    int* bcount     = (int*)w;    w += 256 * 4;          // memset together w/ pooled
    int* row_ptr    = (int*)w;    w += (size_t)(N + 1) * 4;
    u16* wt1        = (u16*)w;    w += (4 * 4096 + 1024) * 2;
    u16* wt2        = (u16*)w;    w += (4 * 4096 + 1024) * 2;
    float* be1      = (float*)w;  w += 16 * 4;
    float* be2      = (float*)w;  w += 16 * 4;
    int* csr_src    = (int*)w;    w += (size_t)E * 4;
    u16* ea16       = (u16*)w;    w += ((size_t)E * 16 + 1024) * 2;
    uint2* bbuf     = (uint2*)w;  w += (size_t)NB * CAP * 8;
    int* gpos       = (int*)w;    w += (size_t)NB * CAP * 4;

    hipMemsetAsync(pooled, 0, (size_t)G * 64 * 4 + 256 * 4, stream);

    wprep_kernel<<<2, 256, 0, stream>>>(wq1, bq1, wk1, wv1, ws1, we1,
                                        wq2, bq2, wk2, wv2, ws2, we2,
                                        wt1, be1, wt2, be2);
    bucket_append<<<(E + EPB - 1) / EPB, 256, 0, stream>>>(dstA, srcA, bcount, bbuf, E, NB);
    csr_index<<<NB, 256, 0, stream>>>(bcount, bbuf, row_ptr, gpos, N, E, NB);
    csr_fill<<<dim3(CAP / 256, NB), 256, 0, stream>>>(bcount, bbuf, gpos, ea,
                                                      csr_src, ea16);

    float* outp = (float*)d_out;
    float* atom = outp + G;

    int qBlocks = (N + 63) / 64;
    int aggBlocks = (N + 3) / 4;

    qkvs_mfma<<<qBlocks, 256, 0, stream>>>(x, wt1, bq1, bk1, bv1, bs1, be1,
                                           qb, kvb, hb, qeb, N);
    agg_kernel<<<aggBlocks, 256, 0, stream>>>(qb, kvb, qeb, we1, ea16, row_ptr, csr_src,
                                              hb, hb, nullptr, nullptr, N);

    qkvs_mfma<<<qBlocks, 256, 0, stream>>>(hb, wt2, bq2, bk2, bv2, bs2, be2,
                                           qb, kvb, atom, qeb, N);
    agg_kernel<<<aggBlocks, 256, 0, stream>>>(qb, kvb, qeb, we2, ea16, row_ptr, csr_src,
                                              atom, atom, batch, pooled, N);

    head_kernel<<<G, 64, 0, stream>>>(pooled, wf1, bf1, wf2, bf2, outp, G);
}

// Round 9
// 361.768 us; speedup vs baseline: 1.5091x; 1.0532x over previous
//
#include <hip/hip_runtime.h>
#include <hip/hip_bf16.h>
#include <math.h>

// UniMP 2-layer TransformerConv. N=50000, E=800000, G=512, D=64 (edge 16).
// R9: CSR build with ONLY coalesced global writes: bucket_append (dense 8B appends),
// csr_index (LDS-staged (s,e) pairs -> fully coalesced csr_se), ea16cvt (edge-order
// bf16 convert, coalesced). agg gathers ea16e[e] (random 32B READS, L3-resident)
// instead of reading a CSR-reordered copy. csr_fill + gpos deleted.

typedef unsigned int uint32;
typedef unsigned short u16;
typedef __attribute__((ext_vector_type(8))) short short8;
typedef __attribute__((ext_vector_type(4))) float f32x4;

#define BW 256        // dsts per bucket
#define CAP 5120      // max edges per bucket (mean 4081, sd ~64 -> +16 sigma)
#define EPB 2048      // edges per block in bucket_append

__device__ __forceinline__ uint32 f2bf(float x) {
    uint32 u = __float_as_uint(x);
    u += 0x7fffu + ((u >> 16) & 1u);
    return u >> 16;
}
__device__ __forceinline__ float bf2f(u16 h) {
    return __uint_as_float(((uint32)h) << 16);
}

// ---------------- bucketed CSR build ----------------

__global__ __launch_bounds__(256) void bucket_append(
    const int* __restrict__ dst, const int* __restrict__ src,
    int* __restrict__ bcount, uint2* __restrict__ buf, int E, int NB)
{
    __shared__ int hist[256], gbase[256], fill[256];
    int t = threadIdx.x;
    hist[t] = 0; fill[t] = 0;
    __syncthreads();
    int e0 = blockIdx.x * EPB;
    int d[8], s[8];
    #pragma unroll
    for (int k = 0; k < 8; ++k) {
        int e = e0 + k * 256 + t;
        if (e < E) {
            d[k] = dst[e]; s[k] = src[e];
            atomicAdd(&hist[d[k] >> 8], 1);
        } else d[k] = -1;
    }
    __syncthreads();
    if (t < NB && hist[t] > 0) gbase[t] = atomicAdd(&bcount[t], hist[t]);
    __syncthreads();
    #pragma unroll
    for (int k = 0; k < 8; ++k) {
        if (d[k] >= 0) {
            int e = e0 + k * 256 + t;
            int b = d[k] >> 8;
            int off = atomicAdd(&fill[b], 1);
            buf[(size_t)b * CAP + gbase[b] + off] =
                make_uint2(((uint32)(d[k] & 255) << 20) | (uint32)e, (uint32)s[k]);
        }
    }
}

// one block per bucket: row_ptr + LDS-staged (s,e) pairs -> coalesced csr_se
__global__ __launch_bounds__(256) void csr_index(
    const int* __restrict__ bcount, const uint2* __restrict__ buf,
    int* __restrict__ row_ptr, uint2* __restrict__ csr_se, int N, int E, int NB)
{
    __shared__ int sc[256], lh[256], lo[256], fill[256];
    __shared__ uint2 se[CAP];
    int t = threadIdx.x;
    int b = blockIdx.x;
    sc[t] = (t < NB) ? bcount[t] : 0;
    lh[t] = 0; fill[t] = 0;
    __syncthreads();
    for (int off = 1; off < 256; off <<= 1) {
        int add = (t >= off) ? sc[t - off] : 0;
        __syncthreads();
        sc[t] += add;
        __syncthreads();
    }
    int cnt = bcount[b];
    int base = sc[b] - cnt;            // exclusive prefix = bucket base in CSR

    const uint2* bb = buf + (size_t)b * CAP;
    for (int i = t; i < cnt; i += 256) atomicAdd(&lh[(int)(bb[i].x >> 20)], 1);
    __syncthreads();
    int v = lh[t];
    lo[t] = v;
    __syncthreads();
    for (int off = 1; off < 256; off <<= 1) {
        int add = (t >= off) ? lo[t - off] : 0;
        __syncthreads();
        lo[t] += add;
        __syncthreads();
    }
    int ex = lo[t] - v;                // exclusive local offset for dst (b*BW+t)
    int d = b * BW + t;
    if (d < N) row_ptr[d] = base + ex;
    if (b == 0 && t == 0) row_ptr[N] = E;
    lo[t] = ex;
    __syncthreads();
    for (int i = t; i < cnt; i += 256) {
        uint2 ent = bb[i];
        int dl = (int)(ent.x >> 20);
        int off = atomicAdd(&fill[dl], 1);
        se[lo[dl] + off] = make_uint2(ent.y, ent.x & 0xFFFFFu);   // (s, e)
    }
    __syncthreads();
    for (int i = t; i < cnt; i += 256) csr_se[base + i] = se[i];   // coalesced
}

// edge-order ea -> bf16 (fully coalesced both ways)
__global__ __launch_bounds__(256) void ea16cvt(const float* __restrict__ ea,
                                               u16* __restrict__ ea16e, int E) {
    int e = blockIdx.x * blockDim.x + threadIdx.x;
    if (e >= E) return;
    const float4* ev = (const float4*)(ea + (size_t)e * 16);
    float4 q0 = ev[0], q1 = ev[1], q2 = ev[2], q3 = ev[3];
    uint32* o = (uint32*)(ea16e + (size_t)e * 16);
    o[0] = f2bf(q0.x) | (f2bf(q0.y) << 16);
    o[1] = f2bf(q0.z) | (f2bf(q0.w) << 16);
    o[2] = f2bf(q1.x) | (f2bf(q1.y) << 16);
    o[3] = f2bf(q1.z) | (f2bf(q1.w) << 16);
    o[4] = f2bf(q2.x) | (f2bf(q2.y) << 16);
    o[5] = f2bf(q2.z) | (f2bf(q2.w) << 16);
    o[6] = f2bf(q3.x) | (f2bf(q3.y) << 16);
    o[7] = f2bf(q3.z) | (f2bf(q3.w) << 16);
}

// ---------------- weight prep: transpose + bf16 for MFMA B-frags ----------------

__global__ void wprep_kernel(
    const float* __restrict__ wq1, const float* __restrict__ bq1,
    const float* __restrict__ wk1, const float* __restrict__ wv1,
    const float* __restrict__ ws1, const float* __restrict__ we1,
    const float* __restrict__ wq2, const float* __restrict__ bq2,
    const float* __restrict__ wk2, const float* __restrict__ wv2,
    const float* __restrict__ ws2, const float* __restrict__ we2,
    u16* __restrict__ wt1, float* __restrict__ be1,
    u16* __restrict__ wt2, float* __restrict__ be2)
{
    int L = blockIdx.x;
    const float* wq = L ? wq2 : wq1;
    const float* bq = L ? bq2 : bq1;
    const float* wk = L ? wk2 : wk1;
    const float* wv = L ? wv2 : wv1;
    const float* ws = L ? ws2 : ws1;
    const float* we = L ? we2 : we1;
    u16* wt = L ? wt2 : wt1;
    float* be = L ? be2 : be1;
    int t = threadIdx.x;
    for (int i = t; i < 4096; i += 256) {
        int k = i >> 6, n = i & 63;
        wt[0 * 4096 + n * 64 + k] = (u16)f2bf(wq[k * 64 + n]);
        wt[1 * 4096 + n * 64 + k] = (u16)f2bf(wk[k * 64 + n]);
        wt[2 * 4096 + n * 64 + k] = (u16)f2bf(wv[k * 64 + n]);
        wt[3 * 4096 + n * 64 + k] = (u16)f2bf(ws[k * 64 + n]);
    }
    for (int i = t; i < 1024; i += 256) {
        int j = i >> 6, k = i & 63;
        float acc = 0.f;
        for (int c = 0; c < 64; ++c) acc = fmaf(wq[k * 64 + c], we[j * 64 + c], acc);
        wt[4 * 4096 + j * 64 + k] = (u16)f2bf(acc * 0.125f);
    }
    if (t < 16) {
        float acc = 0.f;
        for (int c = 0; c < 64; ++c) acc = fmaf(bq[c], we[t * 64 + c], acc);
        be[t] = acc * 0.125f;
    }
}

// ---------------- MFMA fused node linears (no LDS) ----------------

__global__ __launch_bounds__(256) void qkvs_mfma(
    const float* __restrict__ xin, const u16* __restrict__ wt,
    const float* __restrict__ bq, const float* __restrict__ bk,
    const float* __restrict__ bv, const float* __restrict__ bs,
    const float* __restrict__ be,
    float* __restrict__ qo, uint32* __restrict__ kvo,
    float* __restrict__ so, float* __restrict__ qeo, int N)
{
    int wave = threadIdx.x >> 6;
    int lane = threadIdx.x & 63;
    int quad = lane >> 4;
    int l16 = lane & 15;
    int n0 = blockIdx.x * 64 + wave * 16;
    int row = n0 + l16;
    int rn = (row < N) ? row : (N - 1);

    const float4* xr = (const float4*)(xin + (size_t)rn * 64);
    float4 u0 = xr[quad * 2 + 0], u1 = xr[quad * 2 + 1];
    float4 u2 = xr[8 + quad * 2 + 0], u3 = xr[8 + quad * 2 + 1];
    short8 a0, a1;
    a0[0] = (short)f2bf(u0.x); a0[1] = (short)f2bf(u0.y);
    a0[2] = (short)f2bf(u0.z); a0[3] = (short)f2bf(u0.w);
    a0[4] = (short)f2bf(u1.x); a0[5] = (short)f2bf(u1.y);
    a0[6] = (short)f2bf(u1.z); a0[7] = (short)f2bf(u1.w);
    a1[0] = (short)f2bf(u2.x); a1[1] = (short)f2bf(u2.y);
    a1[2] = (short)f2bf(u2.z); a1[3] = (short)f2bf(u2.w);
    a1[4] = (short)f2bf(u3.x); a1[5] = (short)f2bf(u3.y);
    a1[6] = (short)f2bf(u3.z); a1[7] = (short)f2bf(u3.w);

    const short8* w8 = (const short8*)wt;

    f32x4 acc[4][4];
    #pragma unroll
    for (int m = 0; m < 4; ++m)
        #pragma unroll
        for (int c = 0; c < 4; ++c) acc[m][c] = (f32x4){0.f, 0.f, 0.f, 0.f};
    f32x4 aqe = (f32x4){0.f, 0.f, 0.f, 0.f};

    #pragma unroll
    for (int m = 0; m < 4; ++m) {
        #pragma unroll
        for (int c = 0; c < 4; ++c) {
            short8 b0 = w8[m * 512 + (c * 16 + l16) * 8 + quad];
            short8 b1 = w8[m * 512 + (c * 16 + l16) * 8 + 4 + quad];
            acc[m][c] = __builtin_amdgcn_mfma_f32_16x16x32_bf16(a0, b0, acc[m][c], 0, 0, 0);
            acc[m][c] = __builtin_amdgcn_mfma_f32_16x16x32_bf16(a1, b1, acc[m][c], 0, 0, 0);
        }
    }
    {
        short8 b0 = w8[4 * 512 + l16 * 8 + quad];
        short8 b1 = w8[4 * 512 + l16 * 8 + 4 + quad];
        aqe = __builtin_amdgcn_mfma_f32_16x16x32_bf16(a0, b0, aqe, 0, 0, 0);
        aqe = __builtin_amdgcn_mfma_f32_16x16x32_bf16(a1, b1, aqe, 0, 0, 0);
    }

    int node0 = n0 + quad * 4;
    #pragma unroll
    for (int c = 0; c < 4; ++c) {
        int col = c * 16 + l16;
        float bQ = bq[col], bK = bk[col], bV = bv[col], bS = bs[col];
        #pragma unroll
        for (int r = 0; r < 4; ++r) {
            int node = node0 + r;
            if (node < N) {
                size_t off = (size_t)node * 64 + col;
                qo[off] = (acc[0][c][r] + bQ) * 0.125f;
                kvo[off] = f2bf(acc[1][c][r] + bK) | (f2bf(acc[2][c][r] + bV) << 16);
                so[off] = acc[3][c][r] + bS;
            }
        }
    }
    float beL = be[l16];
    #pragma unroll
    for (int r = 0; r < 4; ++r) {
        int node = node0 + r;
        if (node < N) qeo[(size_t)node * 16 + l16] = aqe[r] + beL;
    }
}

// ---------------- per-node softmax aggregation (feature-blocked, 16 edges/iter) -----

__global__ __launch_bounds__(256) void agg_kernel(
    const float* __restrict__ q, const uint32* __restrict__ kv,
    const float* __restrict__ qe, const float* __restrict__ we,
    const u16* __restrict__ ea16e,
    const int* __restrict__ row_ptr, const uint2* __restrict__ csr_se,
    const float* __restrict__ skip_in, float* __restrict__ hout,
    const int* __restrict__ batch, float* __restrict__ pooled, int N)
{
    int lane = threadIdx.x & 63;
    int wid = (blockIdx.x << 2) + (threadIdx.x >> 6);
    if (wid >= N) return;
    int i = __builtin_amdgcn_readfirstlane(wid);

    int grp = lane >> 4;
    int pos = lane & 15;

    float4 qv = ((const float4*)(q + (size_t)i * 64))[pos];
    float qel = qe[(size_t)i * 16 + pos];
    float wer[16];
    #pragma unroll
    for (int j = 0; j < 16; ++j) wer[j] = we[j * 64 + lane];

    float den = 0.f, aj = 0.f;
    float o4x = 0.f, o4y = 0.f, o4z = 0.f, o4w = 0.f;

    int beg = row_ptr[i], end = row_ptr[i + 1];
    int last = end - 1;
    for (int p = beg; p < end; p += 16) {
        #pragma unroll
        for (int c = 0; c < 4; ++c) {
            int eg = p + 4 * c + grp;
            int si = (eg < end) ? eg : last;
            uint2 se = csr_se[si];
            uint4 kb = ((const uint4*)(kv + (size_t)se.x * 64))[pos];
            float eav = bf2f(ea16e[(size_t)se.y * 16 + pos]);
            float pa = eav * qel;
            pa = fmaf(qv.x, __uint_as_float(kb.x << 16), pa);
            pa = fmaf(qv.y, __uint_as_float(kb.y << 16), pa);
            pa = fmaf(qv.z, __uint_as_float(kb.z << 16), pa);
            pa = fmaf(qv.w, __uint_as_float(kb.w << 16), pa);
            pa += __shfl_xor(pa, 1);
            pa += __shfl_xor(pa, 2);
            pa += __shfl_xor(pa, 4);
            pa += __shfl_xor(pa, 8);
            float sc = (eg < end) ? pa : -1e30f;
            float w = __expf(sc);
            den += w;
            aj = fmaf(w, eav, aj);
            o4x = fmaf(w, __uint_as_float(kb.x & 0xffff0000u), o4x);
            o4y = fmaf(w, __uint_as_float(kb.y & 0xffff0000u), o4y);
            o4z = fmaf(w, __uint_as_float(kb.z & 0xffff0000u), o4z);
            o4w = fmaf(w, __uint_as_float(kb.w & 0xffff0000u), o4w);
        }
    }

    o4x += __shfl_xor(o4x, 16); o4x += __shfl_xor(o4x, 32);
    o4y += __shfl_xor(o4y, 16); o4y += __shfl_xor(o4y, 32);
    o4z += __shfl_xor(o4z, 16); o4z += __shfl_xor(o4z, 32);
    o4w += __shfl_xor(o4w, 16); o4w += __shfl_xor(o4w, 32);
    aj  += __shfl_xor(aj, 16);  aj  += __shfl_xor(aj, 32);
    den += __shfl_xor(den, 16); den += __shfl_xor(den, 32);

    int srcl = lane >> 2;
    float t0 = __shfl(o4x, srcl), t1 = __shfl(o4y, srcl);
    float t2 = __shfl(o4z, srcl), t3 = __shfl(o4w, srcl);
    int r2 = lane & 3;
    float o = (r2 == 0) ? t0 : (r2 == 1) ? t1 : (r2 == 2) ? t2 : t3;

    #pragma unroll
    for (int j = 0; j < 16; ++j) o = fmaf(__shfl(aj, j), wer[j], o);

    float dinv = (den > 0.f) ? 1.f / den : 0.f;
    float r = fmaf(o, dinv, skip_in[(size_t)i * 64 + lane]);
    r = (r >= 0.f) ? r : 0.01f * r;
    hout[(size_t)i * 64 + lane] = r;
    if (pooled) atomicAdd(&pooled[(size_t)batch[i] * 64 + lane], r);
}

// ---------------- head ----------------

__global__ void head_kernel(const float* __restrict__ pooled,
                            const float* __restrict__ w1, const float* __restrict__ b1,
                            const float* __restrict__ w2, const float* __restrict__ b2,
                            float* __restrict__ out, int G) {
    int g = blockIdx.x;
    int lane = threadIdx.x;
    __shared__ float hl[64];
    float p = pooled[g * 64 + lane];
    float ss = p * p;
    #pragma unroll
    for (int off = 32; off; off >>= 1) ss += __shfl_xor(ss, off);
    float hn = p / fmaxf(sqrtf(ss), 1e-12f);
    hl[lane] = hn;
    __syncthreads();
    float acc = b1[lane];
    #pragma unroll
    for (int j = 0; j < 64; ++j) acc = fmaf(hl[j], w1[j * 64 + lane], acc);
    acc = (acc >= 0.f) ? acc : 0.01f * acc;
    float r = acc * w2[lane];
    #pragma unroll
    for (int off = 32; off; off >>= 1) r += __shfl_xor(r, off);
    if (lane == 0) out[g] = r + b2[0];
}

// ---------------- launch ----------------

extern "C" void kernel_launch(void* const* d_in, const int* in_sizes, int n_in,
                              void* d_out, int out_size, void* d_ws, size_t ws_size,
                              hipStream_t stream) {
    const float* x     = (const float*)d_in[0];
    const int*   ei    = (const int*)  d_in[1];
    const float* ea    = (const float*)d_in[2];
    const int*   batch = (const int*)  d_in[3];
    const float *wq1=(const float*)d_in[4],  *bq1=(const float*)d_in[5];
    const float *wk1=(const float*)d_in[6],  *bk1=(const float*)d_in[7];
    const float *wv1=(const float*)d_in[8],  *bv1=(const float*)d_in[9];
    const float *we1=(const float*)d_in[10];
    const float *ws1=(const float*)d_in[11], *bs1=(const float*)d_in[12];
    const float *wq2=(const float*)d_in[13], *bq2=(const float*)d_in[14];
    const float *wk2=(const float*)d_in[15], *bk2=(const float*)d_in[16];
    const float *wv2=(const float*)d_in[17], *bv2=(const float*)d_in[18];
    const float *we2=(const float*)d_in[19];
    const float *ws2=(const float*)d_in[20], *bs2=(const float*)d_in[21];
    const float *wf1=(const float*)d_in[22], *bf1=(const float*)d_in[23];
    const float *wf2=(const float*)d_in[24], *bf2=(const float*)d_in[25];

    int N = in_sizes[0] / 64;
    int E = in_sizes[2] / 16;
    int G = out_size - N * 64;
    int NB = (N + BW - 1) / BW;

    const int* srcA = ei;
    const int* dstA = ei + E;

    char* w = (char*)d_ws;
    float*  qb      = (float*)w;  w += (size_t)N * 64 * 4;
    uint32* kvb     = (uint32*)w; w += (size_t)N * 64 * 4;
    float*  hb      = (float*)w;  w += (size_t)N * 64 * 4;
    float*  qeb     = (float*)w;  w += (size_t)N * 16 * 4;
    float*  pooled  = (float*)w;  w += (size_t)G * 64 * 4;
    int* bcount     = (int*)w;    w += 256 * 4;          // memset together w/ pooled
    int* row_ptr    = (int*)w;    w += (size_t)(N + 1) * 4;
    u16* wt1        = (u16*)w;    w += (4 * 4096 + 1024) * 2;
    u16* wt2        = (u16*)w;    w += (4 * 4096 + 1024) * 2;
    float* be1      = (float*)w;  w += 16 * 4;
    float* be2      = (float*)w;  w += 16 * 4;
    uint2* csr_se   = (uint2*)w;  w += (size_t)E * 8;
    u16* ea16e      = (u16*)w;    w += ((size_t)E * 16 + 1024) * 2;
    uint2* bbuf     = (uint2*)w;  w += (size_t)NB * CAP * 8;

    hipMemsetAsync(pooled, 0, (size_t)G * 64 * 4 + 256 * 4, stream);

    wprep_kernel<<<2, 256, 0, stream>>>(wq1, bq1, wk1, wv1, ws1, we1,
                                        wq2, bq2, wk2, wv2, ws2, we2,
                                        wt1, be1, wt2, be2);
    bucket_append<<<(E + EPB - 1) / EPB, 256, 0, stream>>>(dstA, srcA, bcount, bbuf, E, NB);
    ea16cvt<<<(E + 255) / 256, 256, 0, stream>>>(ea, ea16e, E);
    csr_index<<<NB, 256, 0, stream>>>(bcount, bbuf, row_ptr, csr_se, N, E, NB);

    float* outp = (float*)d_out;
    float* atom = outp + G;

    int qBlocks = (N + 63) / 64;
    int aggBlocks = (N + 3) / 4;

    qkvs_mfma<<<qBlocks, 256, 0, stream>>>(x, wt1, bq1, bk1, bv1, bs1, be1,
                                           qb, kvb, hb, qeb, N);
    agg_kernel<<<aggBlocks, 256, 0, stream>>>(qb, kvb, qeb, we1, ea16e, row_ptr, csr_se,
                                              hb, hb, nullptr, nullptr, N);

    qkvs_mfma<<<qBlocks, 256, 0, stream>>>(hb, wt2, bq2, bk2, bv2, bs2, be2,
                                           qb, kvb, atom, qeb, N);
    agg_kernel<<<aggBlocks, 256, 0, stream>>>(qb, kvb, qeb, we2, ea16e, row_ptr, csr_se,
                                              atom, atom, batch, pooled, N);

    head_kernel<<<G, 64, 0, stream>>>(pooled, wf1, bf1, wf2, bf2, outp, G);
}